// Round 4
// baseline (2751.537 us; speedup 1.0000x reference)
//
#include <hip/hip_runtime.h>
#include <math.h>

#define KK 512
#define VV 50257
#define VP 50272   // padded mhq row stride (halfs)
#define DD 768
#define RR 192

#define LAM 0.3f
#define GAM 0.3f
#define L2E 1.44269504088896340736f
#define ENC_NEG_INF 0x007FFFFFu

// fused-sinkhorn geometry: 256 blocks (1/CU, co-resident) x 1024 threads
#define SBLK 256
#define CPB 197    // ceil(VV/SBLK); SBLK*CPB = 50432 >= VV

typedef __bf16 bf16x8 __attribute__((ext_vector_type(8)));
typedef _Float16 f16x8 __attribute__((ext_vector_type(8)));
typedef _Float16 f16x2 __attribute__((ext_vector_type(2)));
typedef unsigned short u16x8 __attribute__((ext_vector_type(8)));
typedef float f32x4 __attribute__((ext_vector_type(4)));

// ---------------------------------------------------------------------------
// helpers
// ---------------------------------------------------------------------------
static __device__ __forceinline__ float get_eps(const float* p_log_eps) {
  return log1pf(expf(p_log_eps[0])) + 0.001f;  // softplus(log_eps)+1e-3
}

static __device__ __forceinline__ float fast_exp2(float x) {
  return __builtin_amdgcn_exp2f(x);  // v_exp_f32 (2^x)
}

// order-preserving float<->unsigned encode for atomicMax
static __device__ __forceinline__ unsigned enc_f(float f) {
  unsigned u = __builtin_bit_cast(unsigned, f);
  return (u & 0x80000000u) ? ~u : (u | 0x80000000u);
}
static __device__ __forceinline__ float dec_f(unsigned e) {
  unsigned u = (e & 0x80000000u) ? (e ^ 0x80000000u) : ~e;
  return __builtin_bit_cast(float, u);
}

// fp32 -> bf16 rne (for the non-eye fallback GEMM only)
static __device__ __forceinline__ unsigned short f2bf(float x) {
  unsigned u = __builtin_bit_cast(unsigned, x);
  u += 0x7fffu + ((u >> 16) & 1u);
  return (unsigned short)(u >> 16);
}
static __device__ __forceinline__ float bf2f(unsigned short h) {
  unsigned u = ((unsigned)h) << 16;
  return __builtin_bit_cast(float, u);
}

// async global->LDS DMA, 16 B per lane. LDS dest is wave-uniform base +
// lane*16 (m104); global src is per-lane.
static __device__ __forceinline__ void gload_lds16(const void* g, void* l) {
  __builtin_amdgcn_global_load_lds(
      (const __attribute__((address_space(1))) unsigned int*)g,
      (__attribute__((address_space(3))) unsigned int*)l, 16, 0, 0);
}

// software grid barrier, device(agent)-scope atomics (XCD-coherent, G16).
// Requires all blocks co-resident: grid=256 x 1-block/CU guarantees it.
static __device__ __forceinline__ void gbar(unsigned* cnt, unsigned* gen) {
  __syncthreads();
  if (threadIdx.x == 0) {
    unsigned g = __hip_atomic_load(gen, __ATOMIC_RELAXED, __HIP_MEMORY_SCOPE_AGENT);
    unsigned a = __hip_atomic_fetch_add(cnt, 1u, __ATOMIC_ACQ_REL, __HIP_MEMORY_SCOPE_AGENT);
    if (a == SBLK - 1) {
      __hip_atomic_store(cnt, 0u, __ATOMIC_RELAXED, __HIP_MEMORY_SCOPE_AGENT);
      __hip_atomic_fetch_add(gen, 1u, __ATOMIC_ACQ_REL, __HIP_MEMORY_SCOPE_AGENT);
    } else {
      while (__hip_atomic_load(gen, __ATOMIC_ACQUIRE, __HIP_MEMORY_SCOPE_AGENT) == g)
        __builtin_amdgcn_s_sleep(2);
    }
  }
  __syncthreads();
}

// ---------------------------------------------------------------------------
// prep: fused small-kernel pass.
//  blocks [0,576):     Ut16[r,d] = fp16(U[d,r])
//  blocks [576,773):   lv2 = 0 (50264 incl pad)
//  block 773:          slots init (Mv/Mu maxima, eye flag, barrier cnt/gen)
//  blocks [774,1286):  a16 = fp16(normalize(anchors)), one block per row
//  blocks [1286,1308): SS[11][512] = 0 (sinkhorn partial-sum slots)
// slots: [0..11]=Mv2, [12..23]=Mu2, [24]=eye_flag, [25]=bar_cnt, [26]=bar_gen
// ---------------------------------------------------------------------------
__global__ __launch_bounds__(256)
void prep(const float* __restrict__ U, float* __restrict__ lv2,
          unsigned* __restrict__ slots, const float* __restrict__ anchors,
          _Float16* __restrict__ Ut16, _Float16* __restrict__ a16,
          float* __restrict__ SS) {
  int bid = blockIdx.x;
  int t = threadIdx.x;
  if (bid < 576) {
    int idx = bid * 256 + t;
    int r = idx / DD;
    int d = idx - r * DD;
    Ut16[idx] = (_Float16)U[(size_t)d * RR + r];
  } else if (bid < 773) {
    int i = (bid - 576) * 256 + t;
    if (i < 50264) lv2[i] = 0.f;
  } else if (bid == 773) {
    if (t < 24) slots[t] = (t == 0) ? 0x80000000u : ENC_NEG_INF;  // enc(0), enc(-inf)
    if (t == 24) slots[24] = 1u;                                  // eye_flag
    if (t >= 25 && t < 32) slots[t] = 0u;                         // barrier state
  } else if (bid < 1286) {
    int r = bid - 774;
    const float* x = anchors + (size_t)r * DD;
    float v0 = x[t], v1 = x[t + 256], v2 = x[t + 512];
    __shared__ float red[256];
    red[t] = v0 * v0 + v1 * v1 + v2 * v2;
    __syncthreads();
    for (int off = 128; off > 0; off >>= 1) {
      if (t < off) red[t] += red[t + off];
      __syncthreads();
    }
    float inv = 1.0f / fmaxf(sqrtf(red[0]), 1e-12f);
    _Float16* y = a16 + (size_t)r * DD;
    y[t] = (_Float16)(v0 * inv);
    y[t + 256] = (_Float16)(v1 * inv);
    y[t + 512] = (_Float16)(v2 * inv);
  } else {
    int idx = (bid - 1286) * 256 + t;
    if (idx < 11 * KK) SS[idx] = 0.f;
  }
}

// ---------------------------------------------------------------------------
// check Wp == I (exact); clears eye flag on mismatch
// ---------------------------------------------------------------------------
__global__ __launch_bounds__(256)
void check_eye(const float* __restrict__ Wp, unsigned* __restrict__ flag) {
  int i = blockIdx.x * 256 + threadIdx.x;
  if (i >= DD * DD) return;
  int r = i / DD;
  int c = i - r * DD;
  float expect = (r == c) ? 1.f : 0.f;
  if (Wp[i] != expect) atomicAnd(flag, 0u);
}

// ---------------------------------------------------------------------------
// FALLBACK ONLY (Wp != I): split-bf16 3-term GEMM w_raw = WE @ Wp^T -> fp16.
// When *eyeflag, returns immediately (norm_w reads WE directly).
// ---------------------------------------------------------------------------
#define BM 128
#define BN 128
#define BK 32
#define LDKB 40  // bf16 fallback LDS stride
#define LDK 40   // fp16 LDS stride (pad -> 2-way banks, free)

__global__ __launch_bounds__(256, 2)
void gemm_we_fallback(const float* __restrict__ A, const float* __restrict__ B,
                      _Float16* __restrict__ C, int M, int N, int Kd,
                      const unsigned* __restrict__ eyeflag) {
  if (*eyeflag) return;
  __shared__ unsigned short As[2][BM][LDKB];
  __shared__ unsigned short Bs[2][BN][LDKB];
  const int tid = threadIdx.x;
  const int bm = blockIdx.y * BM;
  const int bn = blockIdx.x * BN;
  const int srow = tid >> 1;
  const int skb = (tid & 1) << 4;
  const int wave = tid >> 6;
  const int lane = tid & 63;
  const int wm = (wave >> 1) << 6;
  const int wn = (wave & 1) << 6;
  const int lm = lane & 15;
  const int quad = lane >> 4;
  f32x4 acc[4][4];
#pragma unroll
  for (int i = 0; i < 4; ++i)
#pragma unroll
    for (int j = 0; j < 4; ++j) acc[i][j] = (f32x4){0.f, 0.f, 0.f, 0.f};
  const int ra = bm + srow;
  const int rb = bn + srow;
  for (int k0 = 0; k0 < Kd; k0 += BK) {
    float va[16], vb[16];
    if (ra < M) {
      const float4* p = (const float4*)(A + (size_t)ra * Kd + k0 + skb);
      ((float4*)va)[0] = p[0]; ((float4*)va)[1] = p[1];
      ((float4*)va)[2] = p[2]; ((float4*)va)[3] = p[3];
    } else {
#pragma unroll
      for (int q = 0; q < 16; ++q) va[q] = 0.f;
    }
    if (rb < N) {
      const float4* p = (const float4*)(B + (size_t)rb * Kd + k0 + skb);
      ((float4*)vb)[0] = p[0]; ((float4*)vb)[1] = p[1];
      ((float4*)vb)[2] = p[2]; ((float4*)vb)[3] = p[3];
    } else {
#pragma unroll
      for (int q = 0; q < 16; ++q) vb[q] = 0.f;
    }
    __syncthreads();
    {
      u16x8 h0, h1, l0, l1;
#pragma unroll
      for (int q = 0; q < 8; ++q) {
        unsigned short h = f2bf(va[q]);
        h0[q] = h; l0[q] = f2bf(va[q] - bf2f(h));
        h = f2bf(va[q + 8]);
        h1[q] = h; l1[q] = f2bf(va[q + 8] - bf2f(h));
      }
      *(u16x8*)&As[0][srow][skb] = h0; *(u16x8*)&As[0][srow][skb + 8] = h1;
      *(u16x8*)&As[1][srow][skb] = l0; *(u16x8*)&As[1][srow][skb + 8] = l1;
#pragma unroll
      for (int q = 0; q < 8; ++q) {
        unsigned short h = f2bf(vb[q]);
        h0[q] = h; l0[q] = f2bf(vb[q] - bf2f(h));
        h = f2bf(vb[q + 8]);
        h1[q] = h; l1[q] = f2bf(vb[q + 8] - bf2f(h));
      }
      *(u16x8*)&Bs[0][srow][skb] = h0; *(u16x8*)&Bs[0][srow][skb + 8] = h1;
      *(u16x8*)&Bs[1][srow][skb] = l0; *(u16x8*)&Bs[1][srow][skb + 8] = l1;
    }
    __syncthreads();
    bf16x8 Ah[4], Al[4], Bh[4], Bl[4];
#pragma unroll
    for (int i = 0; i < 4; ++i) {
      Ah[i] = *(const bf16x8*)&As[0][wm + i * 16 + lm][quad * 8];
      Al[i] = *(const bf16x8*)&As[1][wm + i * 16 + lm][quad * 8];
      Bh[i] = *(const bf16x8*)&Bs[0][wn + i * 16 + lm][quad * 8];
      Bl[i] = *(const bf16x8*)&Bs[1][wn + i * 16 + lm][quad * 8];
    }
#pragma unroll
    for (int i = 0; i < 4; ++i)
#pragma unroll
      for (int j = 0; j < 4; ++j) {
        acc[i][j] = __builtin_amdgcn_mfma_f32_16x16x32_bf16(Ah[i], Bh[j], acc[i][j], 0, 0, 0);
        acc[i][j] = __builtin_amdgcn_mfma_f32_16x16x32_bf16(Ah[i], Bl[j], acc[i][j], 0, 0, 0);
        acc[i][j] = __builtin_amdgcn_mfma_f32_16x16x32_bf16(Al[i], Bh[j], acc[i][j], 0, 0, 0);
      }
  }
#pragma unroll
  for (int i = 0; i < 4; ++i)
#pragma unroll
    for (int j = 0; j < 4; ++j) {
      int col = bn + wn + j * 16 + lm;
#pragma unroll
      for (int r = 0; r < 4; ++r) {
        int row = bm + wm + i * 16 + quad * 4 + r;
        if (row < M && col < N) C[(size_t)row * N + col] = (_Float16)acc[i][j][r];
      }
    }
}

// ---------------------------------------------------------------------------
// norm_w: w16[r,:] = fp16(normalize(src[r,:])), src = eye ? WE(f32) : w16(f16)
// ---------------------------------------------------------------------------
__global__ __launch_bounds__(256)
void norm_w(const float* __restrict__ WE, _Float16* __restrict__ w16,
            const unsigned* __restrict__ eyeflag) {
  int r = blockIdx.x;
  int t = threadIdx.x;
  float v0, v1, v2;
  if (*eyeflag) {
    const float* x = WE + (size_t)r * DD;
    v0 = x[t]; v1 = x[t + 256]; v2 = x[t + 512];
  } else {
    const _Float16* x = w16 + (size_t)r * DD;
    v0 = (float)x[t]; v1 = (float)x[t + 256]; v2 = (float)x[t + 512];
  }
  __shared__ float red[256];
  red[t] = v0 * v0 + v1 * v1 + v2 * v2;
  __syncthreads();
  for (int off = 128; off > 0; off >>= 1) {
    if (t < off) red[t] += red[t + off];
    __syncthreads();
  }
  float inv = 1.0f / fmaxf(sqrtf(red[0]), 1e-12f);
  _Float16* y = w16 + (size_t)r * DD;
  y[t] = (_Float16)(v0 * inv);
  y[t + 256] = (_Float16)(v1 * inv);
  y[t + 512] = (_Float16)(v2 * inv);
}

// ---------------------------------------------------------------------------
// fp16 single-term MFMA GEMM: C[M,N] = A[M,Kd]*B[N,Kd]^T. 128x128 tile, BK=32,
// 4 waves x 4x4 frags of mfma_f32_16x16x32_f16. F16OUT: fp16 or fp32 C.
// ---------------------------------------------------------------------------
template <int F16OUT>
__global__ __launch_bounds__(256, 2)
void gemm16(const _Float16* __restrict__ A, const _Float16* __restrict__ B,
            void* __restrict__ Cv, int M, int N, int Kd) {
  __shared__ _Float16 As[BM][LDK];
  __shared__ _Float16 Bs[BN][LDK];
  const int tid = threadIdx.x;
  const int bm = blockIdx.y * BM;
  const int bn = blockIdx.x * BN;
  const int srow = tid >> 1;
  const int skb = (tid & 1) << 4;
  const int wave = tid >> 6;
  const int lane = tid & 63;
  const int wm = (wave >> 1) << 6;
  const int wn = (wave & 1) << 6;
  const int lm = lane & 15;
  const int quad = lane >> 4;
  f32x4 acc[4][4];
#pragma unroll
  for (int i = 0; i < 4; ++i)
#pragma unroll
    for (int j = 0; j < 4; ++j) acc[i][j] = (f32x4){0.f, 0.f, 0.f, 0.f};
  const int ra = bm + srow;
  const int rb = bn + srow;
  for (int k0 = 0; k0 < Kd; k0 += BK) {
    f16x8 a0 = (f16x8)(_Float16)0, a1 = a0, b0 = a0, b1 = a0;
    if (ra < M) {
      const f16x8* p = (const f16x8*)(A + (size_t)ra * Kd + k0 + skb);
      a0 = p[0]; a1 = p[1];
    }
    if (rb < N) {
      const f16x8* p = (const f16x8*)(B + (size_t)rb * Kd + k0 + skb);
      b0 = p[0]; b1 = p[1];
    }
    __syncthreads();
    *(f16x8*)&As[srow][skb] = a0; *(f16x8*)&As[srow][skb + 8] = a1;
    *(f16x8*)&Bs[srow][skb] = b0; *(f16x8*)&Bs[srow][skb + 8] = b1;
    __syncthreads();
    f16x8 Af[4], Bf[4];
#pragma unroll
    for (int i = 0; i < 4; ++i) {
      Af[i] = *(const f16x8*)&As[wm + i * 16 + lm][quad * 8];
      Bf[i] = *(const f16x8*)&Bs[wn + i * 16 + lm][quad * 8];
    }
#pragma unroll
    for (int i = 0; i < 4; ++i)
#pragma unroll
      for (int j = 0; j < 4; ++j)
        acc[i][j] = __builtin_amdgcn_mfma_f32_16x16x32_f16(Af[i], Bf[j], acc[i][j], 0, 0, 0);
  }
#pragma unroll
  for (int i = 0; i < 4; ++i)
#pragma unroll
    for (int j = 0; j < 4; ++j) {
      int col = bn + wn + j * 16 + lm;
#pragma unroll
      for (int r = 0; r < 4; ++r) {
        int row = bm + wm + i * 16 + quad * 4 + r;
        if (row < M && col < N) {
          if (F16OUT)
            ((_Float16*)Cv)[(size_t)row * N + col] = (_Float16)acc[i][j][r];
          else
            ((float*)Cv)[(size_t)row * N + col] = acc[i][j][r];
        }
      }
    }
}

// ---------------------------------------------------------------------------
// FUSED S+P GEMM (roomy path): global_load_lds staging + 2-phase dbuf
// pipeline with counted vmcnt (unchanged from R3; 120 us, latency-bound).
// ---------------------------------------------------------------------------
__global__ __launch_bounds__(256, 2)
void gemm_sp(const _Float16* __restrict__ Aw, const _Float16* __restrict__ Bw,
             const _Float16* __restrict__ Au, const _Float16* __restrict__ Bu,
             float* __restrict__ Sd, _Float16* __restrict__ mhq,
             const float* __restrict__ AAv, const float* __restrict__ BBv,
             const float* __restrict__ tbias,
             const float* __restrict__ p_log_scale,
             const float* __restrict__ p_log_eps, int M, int N) {
  __shared__ _Float16 As[2][BM][32];   // 2 x 8 KB
  __shared__ _Float16 Bs[2][BM][32];   // 2 x 8 KB
  const int tid = threadIdx.x;
  const int bm = blockIdx.x * BM;   // K-rows: 4 blocks
  const int bn = blockIdx.y * BN;   // V-cols: 393 blocks
  const int wave = tid >> 6;
  const int lane = tid & 63;
  const int wm = (wave >> 1) << 6;
  const int wn = (wave & 1) << 6;
  const int lm = lane & 15;
  const int quad = lane >> 4;

  const int c0 = wave * 2;
  const int r0 = c0 * 16 + (lane >> 2);
  const int r1 = r0 + 16;
  const int gp = lane & 3;
  const int gg0 = gp ^ ((r0 >> 1) & 3);
  const int gg1 = gp ^ ((r1 >> 1) & 3);

  const _Float16* pAu0 = Au + (size_t)(bm + r0) * RR + gg0 * 8;
  const _Float16* pAu1 = Au + (size_t)(bm + r1) * RR + gg1 * 8;
  const _Float16* pBu0 = Bu + (size_t)(bn + r0) * RR + gg0 * 8;
  const _Float16* pBu1 = Bu + (size_t)(bn + r1) * RR + gg1 * 8;
  const _Float16* pAw0 = Aw + (size_t)(bm + r0) * DD + gg0 * 8;
  const _Float16* pAw1 = Aw + (size_t)(bm + r1) * DD + gg1 * 8;
  const _Float16* pBw0 = Bw + (size_t)(bn + r0) * DD + gg0 * 8;
  const _Float16* pBw1 = Bw + (size_t)(bn + r1) * DD + gg1 * 8;

  auto stage = [&](int t, int buf) {
    _Float16* la = &As[buf][0][0] + c0 * 512;
    _Float16* lb = &Bs[buf][0][0] + c0 * 512;
    if (t < 6) {
      int k0 = t * BK;
      gload_lds16(pAu0 + k0, la);
      gload_lds16(pAu1 + k0, la + 512);
      gload_lds16(pBu0 + k0, lb);
      gload_lds16(pBu1 + k0, lb + 512);
    } else {
      int k0 = (t - 6) * BK;
      gload_lds16(pAw0 + k0, la);
      gload_lds16(pAw1 + k0, la + 512);
      gload_lds16(pBw0 + k0, lb);
      gload_lds16(pBw1 + k0, lb + 512);
    }
  };

  f32x4 accP[4][4], accS[4][4];
#pragma unroll
  for (int i = 0; i < 4; ++i)
#pragma unroll
    for (int j = 0; j < 4; ++j) {
      accP[i][j] = (f32x4){0.f, 0.f, 0.f, 0.f};
      accS[i][j] = (f32x4){0.f, 0.f, 0.f, 0.f};
    }

  stage(0, 0);
  for (int t = 0; t < 6; ++t) {
    const int cur = t & 1;
    stage(t + 1, cur ^ 1);
    asm volatile("s_waitcnt vmcnt(4)" ::: "memory");
    __builtin_amdgcn_s_barrier();
    asm volatile("" ::: "memory");
    f16x8 Af[4], Bf[4];
#pragma unroll
    for (int i = 0; i < 4; ++i) {
      int ra_ = wm + i * 16 + lm;
      int rb_ = wn + i * 16 + lm;
      Af[i] = *(const f16x8*)&As[cur][ra_][(quad ^ ((ra_ >> 1) & 3)) * 8];
      Bf[i] = *(const f16x8*)&Bs[cur][rb_][(quad ^ ((rb_ >> 1) & 3)) * 8];
    }
#pragma unroll
    for (int i = 0; i < 4; ++i)
#pragma unroll
      for (int j = 0; j < 4; ++j)
        accP[i][j] = __builtin_amdgcn_mfma_f32_16x16x32_f16(Af[i], Bf[j], accP[i][j], 0, 0, 0);
    asm volatile("" ::: "memory");
    __builtin_amdgcn_s_barrier();
  }
  for (int t = 6; t < 30; ++t) {
    const int cur = t & 1;
    if (t < 29) {
      stage(t + 1, cur ^ 1);
      asm volatile("s_waitcnt vmcnt(4)" ::: "memory");
    } else {
      asm volatile("s_waitcnt vmcnt(0)" ::: "memory");
    }
    __builtin_amdgcn_s_barrier();
    asm volatile("" ::: "memory");
    f16x8 Af[4], Bf[4];
#pragma unroll
    for (int i = 0; i < 4; ++i) {
      int ra_ = wm + i * 16 + lm;
      int rb_ = wn + i * 16 + lm;
      Af[i] = *(const f16x8*)&As[cur][ra_][(quad ^ ((ra_ >> 1) & 3)) * 8];
      Bf[i] = *(const f16x8*)&Bs[cur][rb_][(quad ^ ((rb_ >> 1) & 3)) * 8];
    }
#pragma unroll
    for (int i = 0; i < 4; ++i)
#pragma unroll
      for (int j = 0; j < 4; ++j)
        accS[i][j] = __builtin_amdgcn_mfma_f32_16x16x32_f16(Af[i], Bf[j], accS[i][j], 0, 0, 0);
    asm volatile("" ::: "memory");
    __builtin_amdgcn_s_barrier();
  }

  float scale = fminf(expf(p_log_scale[0]), 20.f);
  float qs = L2E / get_eps(p_log_eps);
#pragma unroll
  for (int i = 0; i < 4; ++i)
#pragma unroll
    for (int j = 0; j < 4; ++j) {
      int col = bn + wn + j * 16 + lm;
      if (col >= N) continue;
      float BB = BBv[col];
#pragma unroll
      for (int r = 0; r < 4; ++r) {
        int row = bm + wm + i * 16 + quad * 4 + r;
        float S = accS[i][j][r];
        float mh = fmaxf(AAv[row] + BB - 2.f * (S + accP[i][j][r]), 0.f);
        Sd[(size_t)row * N + col] = fmaf(scale, S, tbias[row]);
        mhq[(size_t)row * VP + col] = (_Float16)(mh * qs);
      }
    }
}

// ---------------------------------------------------------------------------
// P-GEMM + fused epilogue (tight-workspace fallback)
// ---------------------------------------------------------------------------
__global__ __launch_bounds__(256, 2)
void gemm16_p(const _Float16* __restrict__ A, const _Float16* __restrict__ B,
              float* __restrict__ Sd, _Float16* __restrict__ mhq,
              const float* __restrict__ AAv, const float* __restrict__ BBv,
              const float* __restrict__ tbias,
              const float* __restrict__ p_log_scale,
              const float* __restrict__ p_log_eps, int M, int N, int Kd) {
  __shared__ _Float16 As[BM][LDK];
  __shared__ _Float16 Bs[BN][LDK];
  const int tid = threadIdx.x;
  const int bm = blockIdx.y * BM;
  const int bn = blockIdx.x * BN;
  const int srow = tid >> 1;
  const int skb = (tid & 1) << 4;
  const int wave = tid >> 6;
  const int lane = tid & 63;
  const int wm = (wave >> 1) << 6;
  const int wn = (wave & 1) << 6;
  const int lm = lane & 15;
  const int quad = lane >> 4;
  f32x4 acc[4][4];
#pragma unroll
  for (int i = 0; i < 4; ++i)
#pragma unroll
    for (int j = 0; j < 4; ++j) acc[i][j] = (f32x4){0.f, 0.f, 0.f, 0.f};
  const int ra = bm + srow;
  const int rb = bn + srow;
  for (int k0 = 0; k0 < Kd; k0 += BK) {
    f16x8 a0 = (f16x8)(_Float16)0, a1 = a0, b0 = a0, b1 = a0;
    if (ra < M) {
      const f16x8* p = (const f16x8*)(A + (size_t)ra * Kd + k0 + skb);
      a0 = p[0]; a1 = p[1];
    }
    if (rb < N) {
      const f16x8* p = (const f16x8*)(B + (size_t)rb * Kd + k0 + skb);
      b0 = p[0]; b1 = p[1];
    }
    __syncthreads();
    *(f16x8*)&As[srow][skb] = a0; *(f16x8*)&As[srow][skb + 8] = a1;
    *(f16x8*)&Bs[srow][skb] = b0; *(f16x8*)&Bs[srow][skb + 8] = b1;
    __syncthreads();
    f16x8 Af[4], Bf[4];
#pragma unroll
    for (int i = 0; i < 4; ++i) {
      Af[i] = *(const f16x8*)&As[wm + i * 16 + lm][quad * 8];
      Bf[i] = *(const f16x8*)&Bs[wn + i * 16 + lm][quad * 8];
    }
#pragma unroll
    for (int i = 0; i < 4; ++i)
#pragma unroll
      for (int j = 0; j < 4; ++j)
        acc[i][j] = __builtin_amdgcn_mfma_f32_16x16x32_f16(Af[i], Bf[j], acc[i][j], 0, 0, 0);
  }
  float scale = fminf(expf(p_log_scale[0]), 20.f);
  float qs = L2E / get_eps(p_log_eps);
#pragma unroll
  for (int i = 0; i < 4; ++i)
#pragma unroll
    for (int j = 0; j < 4; ++j) {
      int col = bn + wn + j * 16 + lm;
      if (col >= N) continue;
      float BB = BBv[col];
#pragma unroll
      for (int r = 0; r < 4; ++r) {
        int row = bm + wm + i * 16 + quad * 4 + r;
        size_t idx = (size_t)row * N + col;
        float S = Sd[idx];
        float mh = fmaxf(AAv[row] + BB - 2.f * (S + acc[i][j][r]), 0.f);
        Sd[idx] = fmaf(scale, S, tbias[row]);
        mhq[(size_t)row * VP + col] = (_Float16)(mh * qs);
      }
    }
}

// ---------------------------------------------------------------------------
// out[r] = 1 + sum(X16[r,:]^2), cols <= 256
// ---------------------------------------------------------------------------
__global__ __launch_bounds__(256)
void row_sumsq16(const _Float16* __restrict__ X, float* __restrict__ out, int cols) {
  int r = blockIdx.x;
  int t = threadIdx.x;
  float x = (t < cols) ? (float)X[(size_t)r * cols + t] : 0.f;
  __shared__ float red[256];
  red[t] = x * x;
  __syncthreads();
  for (int off = 128; off > 0; off >>= 1) {
    if (t < off) red[t] += red[t + off];
    __syncthreads();
  }
  if (t == 0) out[r] = 1.0f + red[0];
}

// ---------------------------------------------------------------------------
// sink_fused: the ENTIRE sinkhorn (10 iterations) + final softmax in ONE
// persistent kernel. Grid = 256 blocks x 1024 threads = 1 block/CU
// (16 waves, 19 KB LDS, VGPR<=128 via launch bounds) -> co-residency
// guaranteed; software grid barrier over device-scope atomics (all
// cross-block data flows through atomics -> XCD-coherent, G16).
//
// Block b owns columns [b*CPB, b*CPB+CPB); lane l owns cols l+64j (j=0..3).
// lv lives in REGISTERS (same lane owns same cols in every phase).
// Per iteration:
//   phase A (rows): wave w covers k in [32w,32w+32): partial row-sums over
//     own cols, exp2(lv-Mv2-q); cross-lane reduce; atomicAdd SS[it][k].
//   gbar.
//   phase B: lu_k = -(Mv2+log2(SS[it][k])) computed redundantly per block
//     (deterministic, no sync); Mu2 = max(lu) local; col-sums with wave
//     k-split + LDS combine -> lv (regs); block-max lv -> atomicMax Mv[it+1].
//   gbar.
// Then phase F (final row sums, logits clipped +-30) -> SS[10]; gbar;
// phase G: out = exp(logit-30)/row_s.  Formulas copied verbatim from the
// legacy final_sum/final_write kernels.
// mhq panel (~200 KB/block) stays L2/L3-hot across all 22 phases.
// ---------------------------------------------------------------------------
__global__ __launch_bounds__(1024, 4)
void sink_fused(const _Float16* __restrict__ mhq, float* __restrict__ out,
                float* __restrict__ SS, unsigned* __restrict__ slots,
                const float* __restrict__ p_log_eps) {
  const int t = threadIdx.x;
  const int wave = t >> 6;
  const int lane = t & 63;
  const int v0 = blockIdx.x * CPB;
  const int k0 = wave * 32;
  unsigned* Mv_slots = slots;       // [0..11]
  unsigned* bar_cnt = slots + 25;
  unsigned* bar_gen = slots + 26;

  __shared__ float lus[KK];          // 2 KB
  __shared__ float part[16][CPB];    // 12.6 KB
  __shared__ float red[1024];        // 4 KB

  int cs[4]; float lv_reg[4]; bool cval[4];
#pragma unroll
  for (int j = 0; j < 4; ++j) {
    int cl = lane + 64 * j;
    bool v = (cl < CPB) && (v0 + cl < VV);
    cval[j] = v;
    cs[j] = v ? (v0 + cl) : v0;  // clamp to a valid, written column
    lv_reg[j] = 0.f;             // initial lv = 0 (matches prep's lv2=0)
  }

  for (int it = 0; it < 10; ++it) {
    float Mv2 = dec_f(__hip_atomic_load(Mv_slots + it, __ATOMIC_ACQUIRE,
                                        __HIP_MEMORY_SCOPE_AGENT));
    float lvm[4];
#pragma unroll
    for (int j = 0; j < 4; ++j) lvm[j] = cval[j] ? (lv_reg[j] - Mv2) : -1e30f;
    // ---- phase A: partial row sums over own cols ----
    for (int r = k0; r < k0 + 32; ++r) {
      const _Float16* mr = mhq + (size_t)r * VP;
      float s = 0.f;
#pragma unroll
      for (int j = 0; j < 4; ++j)
        s += fast_exp2(lvm[j] - (float)mr[cs[j]]);
#pragma unroll
      for (int off = 32; off > 0; off >>= 1) s += __shfl_xor(s, off);
      if (lane == 0) atomicAdd(&SS[it * KK + r], s);
    }
    gbar(bar_cnt, bar_gen);
    // ---- phase B: lu (redundant per block), Mu2, col sums -> lv ----
    if (t < KK)
      lus[t] = -(Mv2 + log2f(__hip_atomic_load(&SS[it * KK + t],
                                               __ATOMIC_RELAXED,
                                               __HIP_MEMORY_SCOPE_AGENT)));
    __syncthreads();
    if (t < 512) red[t] = lus[t];
    __syncthreads();
    for (int off = 256; off > 0; off >>= 1) {
      if (t < off) red[t] = fmaxf(red[t], red[t + off]);
      __syncthreads();
    }
    float Mu2 = red[0];
    __syncthreads();
    float ps[4] = {0.f, 0.f, 0.f, 0.f};
    for (int k = k0; k < k0 + 32; ++k) {
      float lm = lus[k] - Mu2;
      const _Float16* mr = mhq + (size_t)k * VP;
#pragma unroll
      for (int j = 0; j < 4; ++j)
        ps[j] += fast_exp2(lm - (float)mr[cs[j]]);
    }
#pragma unroll
    for (int j = 0; j < 4; ++j) {
      int cl = lane + 64 * j;
      if (cl < CPB) part[wave][cl] = ps[j];
    }
    __syncthreads();
    float mymax = -1e38f;
#pragma unroll
    for (int j = 0; j < 4; ++j) {
      if (cval[j]) {
        float ssum = 0.f;
#pragma unroll
        for (int w = 0; w < 16; ++w) ssum += part[w][lane + 64 * j];
        float lv = -(Mu2 + log2f(ssum));
        lv_reg[j] = lv;
        mymax = fmaxf(mymax, lv);
      }
    }
    if (wave == 0 && it < 9) {
#pragma unroll
      for (int off = 32; off > 0; off >>= 1)
        mymax = fmaxf(mymax, __shfl_xor(mymax, off));
      if (lane == 0) atomicMax(Mv_slots + it + 1, enc_f(mymax));
    }
    gbar(bar_cnt, bar_gen);   // Mv[it+1] complete; part/lus safe to reuse
  }
  // ---- phase F: final row sums (formula == legacy final_sum) ----
  float eps = get_eps(p_log_eps);
  float c2 = (LAM * eps + GAM) / L2E;
  float c3 = GAM / L2E;
  for (int r = k0; r < k0 + 32; ++r) {
    const float* drow = out + (size_t)r * VV;
    const _Float16* mr = mhq + (size_t)r * VP;
    float base = c3 * lus[r];
    float s = 0.f;
#pragma unroll
    for (int j = 0; j < 4; ++j) {
      float x = fmaf(-c2, (float)mr[cs[j]], fmaf(c3, lv_reg[j], drow[cs[j]] + base));
      x = fminf(30.f, fmaxf(-30.f, x));
      float term = fast_exp2(fmaf(x, L2E, -30.f * L2E));
      s += cval[j] ? term : 0.f;
    }
#pragma unroll
    for (int off = 32; off > 0; off >>= 1) s += __shfl_xor(s, off);
    if (lane == 0) atomicAdd(&SS[10 * KK + r], s);
  }
  gbar(bar_cnt, bar_gen);
  if (t < KK)
    red[t] = __hip_atomic_load(&SS[10 * KK + t], __ATOMIC_RELAXED,
                               __HIP_MEMORY_SCOPE_AGENT);
  __syncthreads();
  // ---- phase G: write probs (formula == legacy final_write) ----
  for (int k = k0; k < k0 + 32; ++k) {
    float* orow = out + (size_t)k * VV;
    const _Float16* mr = mhq + (size_t)k * VP;
    float base = c3 * lus[k];
    float rs = red[k];
#pragma unroll
    for (int j = 0; j < 4; ++j) {
      if (!cval[j]) continue;
      float x = fmaf(-c2, (float)mr[cs[j]], fmaf(c3, lv_reg[j], orow[cs[j]] + base));
      x = fminf(30.f, fmaxf(-30.f, x));
      orow[cs[j]] = fast_exp2(fmaf(x, L2E, -30.f * L2E)) / rs;
    }
  }
}

// ---------------------------------------------------------------------------
// launch
// ---------------------------------------------------------------------------
extern "C" void kernel_launch(void* const* d_in, const int* in_sizes, int n_in,
                              void* d_out, int out_size, void* d_ws, size_t ws_size,
                              hipStream_t stream) {
  (void)in_sizes; (void)n_in; (void)out_size;
  const float* WE        = (const float*)d_in[0];
  const float* anchors   = (const float*)d_in[1];
  const float* MU        = (const float*)d_in[2];
  const float* log_eps   = (const float*)d_in[3];
  const float* log_scale = (const float*)d_in[4];
  const float* tbias     = (const float*)d_in[5];
  const float* Wp        = (const float*)d_in[6];
  float* out = (float*)d_out;

  const size_t H_W16 = (size_t)VV * DD;
  const size_t H_MHQ = (size_t)KK * VP;
  const size_t H_WU  = (size_t)VV * RR;
  const size_t H_A16 = (size_t)KK * DD;
  const size_t H_AU  = (size_t)KK * RR;
  const size_t H_UT  = (size_t)RR * DD;
  const size_t FB_FLOATS = 102064 + 32 + 11 * KK;  // + slots + SS
  const size_t need_roomy =
      2 * (H_W16 + H_MHQ + H_WU + H_A16 + H_AU + H_UT) + 4 * FB_FLOATS;
  const bool roomy = ws_size >= need_roomy;

  _Float16* hb = (_Float16*)d_ws;
  _Float16* w16 = hb;
  size_t ho = H_W16;
  _Float16* mhq;
  if (roomy) { mhq = hb + ho; ho += H_MHQ; }
  else       { mhq = hb; }                 // alias w16 (dead after S GEMM)
  _Float16* wU16 = hb + ho; ho += H_WU;
  _Float16* a16  = hb + ho; ho += H_A16;
  _Float16* aU16 = hb + ho; ho += H_AU;
  _Float16* Ut16 = hb + ho; ho += H_UT;
  float* fb = (float*)(hb + ho);
  float* BBv   = fb;           // 50264
  float* AAv   = fb + 50264;   // 512
  float* lv2   = fb + 51288;   // 50264 (legacy zero region, kept)
  unsigned* slots = (unsigned*)(fb + 102064);  // 32
  float* SS = fb + 102096;     // [11][512]
  unsigned* eye_flag = slots + 24;

  const int MB_V = (VV + BM - 1) / BM;  // 393

  prep<<<1308, 256, 0, stream>>>(MU, lv2, slots, anchors, Ut16, a16, SS);
  check_eye<<<(DD * DD + 255) / 256, 256, 0, stream>>>(Wp, eye_flag);
  gemm_we_fallback<<<dim3(DD / BN, MB_V), 256, 0, stream>>>(WE, Wp, w16, VV, DD, DD, eye_flag);
  norm_w<<<VV, 256, 0, stream>>>(WE, w16, eye_flag);
  gemm16<1><<<dim3(2, MB_V), 256, 0, stream>>>(w16, Ut16, wU16, VV, RR, DD);
  gemm16<1><<<dim3(2, 4), 256, 0, stream>>>(a16, Ut16, aU16, KK, RR, DD);
  row_sumsq16<<<VV, 256, 0, stream>>>(wU16, BBv, RR);
  row_sumsq16<<<KK, 256, 0, stream>>>(aU16, AAv, RR);
  if (roomy) {
    gemm_sp<<<dim3(4, MB_V), 256, 0, stream>>>(a16, w16, aU16, wU16, out, mhq,
                                               AAv, BBv, tbias, log_scale,
                                               log_eps, KK, VV);
  } else {
    gemm16<0><<<dim3(MB_V, 4), 256, 0, stream>>>(a16, w16, out, KK, VV, DD);
    gemm16_p<<<dim3(MB_V, 4), 256, 0, stream>>>(aU16, wU16, out, mhq, AAv, BBv,
                                                tbias, log_scale, log_eps, KK, VV, RR);
  }
  // entire sinkhorn + final softmax: one persistent kernel
  sink_fused<<<SBLK, 1024, 0, stream>>>(mhq, out, SS, slots, log_eps);
}

// Round 5
// 1154.493 us; speedup vs baseline: 2.3833x; 2.3833x over previous
//
#include <hip/hip_runtime.h>
#include <math.h>

#define KK 512
#define VV 50257
#define VP 50272   // padded mhq row stride (halfs)
#define DD 768
#define RR 192

#define LAM 0.3f
#define GAM 0.3f
#define L2E 1.44269504088896340736f
#define ENC_NEG_INF 0x007FFFFFu

typedef __bf16 bf16x8 __attribute__((ext_vector_type(8)));
typedef _Float16 f16x8 __attribute__((ext_vector_type(8)));
typedef _Float16 f16x4 __attribute__((ext_vector_type(4)));
typedef _Float16 f16x2 __attribute__((ext_vector_type(2)));
typedef unsigned short u16x8 __attribute__((ext_vector_type(8)));
typedef float f32x4 __attribute__((ext_vector_type(4)));

// ---------------------------------------------------------------------------
// helpers
// ---------------------------------------------------------------------------
static __device__ __forceinline__ float get_eps(const float* p_log_eps) {
  return log1pf(expf(p_log_eps[0])) + 0.001f;  // softplus(log_eps)+1e-3
}

static __device__ __forceinline__ float fast_exp2(float x) {
  return __builtin_amdgcn_exp2f(x);  // v_exp_f32 (2^x)
}

// order-preserving float<->unsigned encode for atomicMax
static __device__ __forceinline__ unsigned enc_f(float f) {
  unsigned u = __builtin_bit_cast(unsigned, f);
  return (u & 0x80000000u) ? ~u : (u | 0x80000000u);
}
static __device__ __forceinline__ float dec_f(unsigned e) {
  unsigned u = (e & 0x80000000u) ? (e ^ 0x80000000u) : ~e;
  return __builtin_bit_cast(float, u);
}

// fp32 -> bf16 rne (for the non-eye fallback GEMM only)
static __device__ __forceinline__ unsigned short f2bf(float x) {
  unsigned u = __builtin_bit_cast(unsigned, x);
  u += 0x7fffu + ((u >> 16) & 1u);
  return (unsigned short)(u >> 16);
}
static __device__ __forceinline__ float bf2f(unsigned short h) {
  unsigned u = ((unsigned)h) << 16;
  return __builtin_bit_cast(float, u);
}

// async global->LDS DMA, 16 B per lane. LDS dest is wave-uniform base +
// lane*16 (m104); global src is per-lane.
static __device__ __forceinline__ void gload_lds16(const void* g, void* l) {
  __builtin_amdgcn_global_load_lds(
      (const __attribute__((address_space(1))) unsigned int*)g,
      (__attribute__((address_space(3))) unsigned int*)l, 16, 0, 0);
}

// ---------------------------------------------------------------------------
// prep: fused small-kernel pass.
//  blocks [0,576):    Ut16[r,d] = fp16(U[d,r])
//  blocks [576,773):  lv2 = 0 (50264 incl pad)
//  block 773:         slots init (Mv/Mu maxima, eye flag)
//  blocks [774,1286): a16 = fp16(normalize(anchors)), one block per row
// slots: [0..11]=Mv2, [12..23]=Mu2, [24]=eye_flag
// ---------------------------------------------------------------------------
__global__ __launch_bounds__(256)
void prep(const float* __restrict__ U, float* __restrict__ lv2,
          unsigned* __restrict__ slots, const float* __restrict__ anchors,
          _Float16* __restrict__ Ut16, _Float16* __restrict__ a16) {
  int bid = blockIdx.x;
  int t = threadIdx.x;
  if (bid < 576) {
    int idx = bid * 256 + t;
    int r = idx / DD;
    int d = idx - r * DD;
    Ut16[idx] = (_Float16)U[(size_t)d * RR + r];
  } else if (bid < 773) {
    int i = (bid - 576) * 256 + t;
    if (i < 50264) lv2[i] = 0.f;
  } else if (bid == 773) {
    if (t < 24) slots[t] = (t == 0) ? 0x80000000u : ENC_NEG_INF;  // enc(0), enc(-inf)
    if (t == 24) slots[24] = 1u;                                  // eye_flag
  } else {
    int r = bid - 774;
    const float* x = anchors + (size_t)r * DD;
    float v0 = x[t], v1 = x[t + 256], v2 = x[t + 512];
    __shared__ float red[256];
    red[t] = v0 * v0 + v1 * v1 + v2 * v2;
    __syncthreads();
    for (int off = 128; off > 0; off >>= 1) {
      if (t < off) red[t] += red[t + off];
      __syncthreads();
    }
    float inv = 1.0f / fmaxf(sqrtf(red[0]), 1e-12f);
    _Float16* y = a16 + (size_t)r * DD;
    y[t] = (_Float16)(v0 * inv);
    y[t + 256] = (_Float16)(v1 * inv);
    y[t + 512] = (_Float16)(v2 * inv);
  }
}

// ---------------------------------------------------------------------------
// check Wp == I (exact); clears eye flag on mismatch
// ---------------------------------------------------------------------------
__global__ __launch_bounds__(256)
void check_eye(const float* __restrict__ Wp, unsigned* __restrict__ flag) {
  int i = blockIdx.x * 256 + threadIdx.x;
  if (i >= DD * DD) return;
  int r = i / DD;
  int c = i - r * DD;
  float expect = (r == c) ? 1.f : 0.f;
  if (Wp[i] != expect) atomicAnd(flag, 0u);
}

// ---------------------------------------------------------------------------
// FALLBACK ONLY (Wp != I): split-bf16 3-term GEMM w_raw = WE @ Wp^T -> fp16.
// ---------------------------------------------------------------------------
#define BM 128
#define BN 128
#define BK 32
#define LDKB 40  // bf16 fallback LDS stride
#define LDK 40   // fp16 LDS stride (pad -> 2-way banks, free)

__global__ __launch_bounds__(256, 2)
void gemm_we_fallback(const float* __restrict__ A, const float* __restrict__ B,
                      _Float16* __restrict__ C, int M, int N, int Kd,
                      const unsigned* __restrict__ eyeflag) {
  if (*eyeflag) return;
  __shared__ unsigned short As[2][BM][LDKB];
  __shared__ unsigned short Bs[2][BN][LDKB];
  const int tid = threadIdx.x;
  const int bm = blockIdx.y * BM;
  const int bn = blockIdx.x * BN;
  const int srow = tid >> 1;
  const int skb = (tid & 1) << 4;
  const int wave = tid >> 6;
  const int lane = tid & 63;
  const int wm = (wave >> 1) << 6;
  const int wn = (wave & 1) << 6;
  const int lm = lane & 15;
  const int quad = lane >> 4;
  f32x4 acc[4][4];
#pragma unroll
  for (int i = 0; i < 4; ++i)
#pragma unroll
    for (int j = 0; j < 4; ++j) acc[i][j] = (f32x4){0.f, 0.f, 0.f, 0.f};
  const int ra = bm + srow;
  const int rb = bn + srow;
  for (int k0 = 0; k0 < Kd; k0 += BK) {
    float va[16], vb[16];
    if (ra < M) {
      const float4* p = (const float4*)(A + (size_t)ra * Kd + k0 + skb);
      ((float4*)va)[0] = p[0]; ((float4*)va)[1] = p[1];
      ((float4*)va)[2] = p[2]; ((float4*)va)[3] = p[3];
    } else {
#pragma unroll
      for (int q = 0; q < 16; ++q) va[q] = 0.f;
    }
    if (rb < N) {
      const float4* p = (const float4*)(B + (size_t)rb * Kd + k0 + skb);
      ((float4*)vb)[0] = p[0]; ((float4*)vb)[1] = p[1];
      ((float4*)vb)[2] = p[2]; ((float4*)vb)[3] = p[3];
    } else {
#pragma unroll
      for (int q = 0; q < 16; ++q) vb[q] = 0.f;
    }
    __syncthreads();
    {
      u16x8 h0, h1, l0, l1;
#pragma unroll
      for (int q = 0; q < 8; ++q) {
        unsigned short h = f2bf(va[q]);
        h0[q] = h; l0[q] = f2bf(va[q] - bf2f(h));
        h = f2bf(va[q + 8]);
        h1[q] = h; l1[q] = f2bf(va[q + 8] - bf2f(h));
      }
      *(u16x8*)&As[0][srow][skb] = h0; *(u16x8*)&As[0][srow][skb + 8] = h1;
      *(u16x8*)&As[1][srow][skb] = l0; *(u16x8*)&As[1][srow][skb + 8] = l1;
#pragma unroll
      for (int q = 0; q < 8; ++q) {
        unsigned short h = f2bf(vb[q]);
        h0[q] = h; l0[q] = f2bf(vb[q] - bf2f(h));
        h = f2bf(vb[q + 8]);
        h1[q] = h; l1[q] = f2bf(vb[q + 8] - bf2f(h));
      }
      *(u16x8*)&Bs[0][srow][skb] = h0; *(u16x8*)&Bs[0][srow][skb + 8] = h1;
      *(u16x8*)&Bs[1][srow][skb] = l0; *(u16x8*)&Bs[1][srow][skb + 8] = l1;
    }
    __syncthreads();
    bf16x8 Ah[4], Al[4], Bh[4], Bl[4];
#pragma unroll
    for (int i = 0; i < 4; ++i) {
      Ah[i] = *(const bf16x8*)&As[0][wm + i * 16 + lm][quad * 8];
      Al[i] = *(const bf16x8*)&As[1][wm + i * 16 + lm][quad * 8];
      Bh[i] = *(const bf16x8*)&Bs[0][wn + i * 16 + lm][quad * 8];
      Bl[i] = *(const bf16x8*)&Bs[1][wn + i * 16 + lm][quad * 8];
    }
#pragma unroll
    for (int i = 0; i < 4; ++i)
#pragma unroll
      for (int j = 0; j < 4; ++j) {
        acc[i][j] = __builtin_amdgcn_mfma_f32_16x16x32_bf16(Ah[i], Bh[j], acc[i][j], 0, 0, 0);
        acc[i][j] = __builtin_amdgcn_mfma_f32_16x16x32_bf16(Ah[i], Bl[j], acc[i][j], 0, 0, 0);
        acc[i][j] = __builtin_amdgcn_mfma_f32_16x16x32_bf16(Al[i], Bh[j], acc[i][j], 0, 0, 0);
      }
  }
#pragma unroll
  for (int i = 0; i < 4; ++i)
#pragma unroll
    for (int j = 0; j < 4; ++j) {
      int col = bn + wn + j * 16 + lm;
#pragma unroll
      for (int r = 0; r < 4; ++r) {
        int row = bm + wm + i * 16 + quad * 4 + r;
        if (row < M && col < N) C[(size_t)row * N + col] = (_Float16)acc[i][j][r];
      }
    }
}

// ---------------------------------------------------------------------------
// norm_w: w16[r,:] = fp16(normalize(src[r,:])), src = eye ? WE(f32) : w16(f16)
// ---------------------------------------------------------------------------
__global__ __launch_bounds__(256)
void norm_w(const float* __restrict__ WE, _Float16* __restrict__ w16,
            const unsigned* __restrict__ eyeflag) {
  int r = blockIdx.x;
  int t = threadIdx.x;
  float v0, v1, v2;
  if (*eyeflag) {
    const float* x = WE + (size_t)r * DD;
    v0 = x[t]; v1 = x[t + 256]; v2 = x[t + 512];
  } else {
    const _Float16* x = w16 + (size_t)r * DD;
    v0 = (float)x[t]; v1 = (float)x[t + 256]; v2 = (float)x[t + 512];
  }
  __shared__ float red[256];
  red[t] = v0 * v0 + v1 * v1 + v2 * v2;
  __syncthreads();
  for (int off = 128; off > 0; off >>= 1) {
    if (t < off) red[t] += red[t + off];
    __syncthreads();
  }
  float inv = 1.0f / fmaxf(sqrtf(red[0]), 1e-12f);
  _Float16* y = w16 + (size_t)r * DD;
  y[t] = (_Float16)(v0 * inv);
  y[t + 256] = (_Float16)(v1 * inv);
  y[t + 512] = (_Float16)(v2 * inv);
}

// ---------------------------------------------------------------------------
// fp16 single-term MFMA GEMM: C[M,N] = A[M,Kd]*B[N,Kd]^T. 128x128 tile, BK=32.
// ---------------------------------------------------------------------------
template <int F16OUT>
__global__ __launch_bounds__(256, 2)
void gemm16(const _Float16* __restrict__ A, const _Float16* __restrict__ B,
            void* __restrict__ Cv, int M, int N, int Kd) {
  __shared__ _Float16 As[BM][LDK];
  __shared__ _Float16 Bs[BN][LDK];
  const int tid = threadIdx.x;
  const int bm = blockIdx.y * BM;
  const int bn = blockIdx.x * BN;
  const int srow = tid >> 1;
  const int skb = (tid & 1) << 4;
  const int wave = tid >> 6;
  const int lane = tid & 63;
  const int wm = (wave >> 1) << 6;
  const int wn = (wave & 1) << 6;
  const int lm = lane & 15;
  const int quad = lane >> 4;
  f32x4 acc[4][4];
#pragma unroll
  for (int i = 0; i < 4; ++i)
#pragma unroll
    for (int j = 0; j < 4; ++j) acc[i][j] = (f32x4){0.f, 0.f, 0.f, 0.f};
  const int ra = bm + srow;
  const int rb = bn + srow;
  for (int k0 = 0; k0 < Kd; k0 += BK) {
    f16x8 a0 = (f16x8)(_Float16)0, a1 = a0, b0 = a0, b1 = a0;
    if (ra < M) {
      const f16x8* p = (const f16x8*)(A + (size_t)ra * Kd + k0 + skb);
      a0 = p[0]; a1 = p[1];
    }
    if (rb < N) {
      const f16x8* p = (const f16x8*)(B + (size_t)rb * Kd + k0 + skb);
      b0 = p[0]; b1 = p[1];
    }
    __syncthreads();
    *(f16x8*)&As[srow][skb] = a0; *(f16x8*)&As[srow][skb + 8] = a1;
    *(f16x8*)&Bs[srow][skb] = b0; *(f16x8*)&Bs[srow][skb + 8] = b1;
    __syncthreads();
    f16x8 Af[4], Bf[4];
#pragma unroll
    for (int i = 0; i < 4; ++i) {
      Af[i] = *(const f16x8*)&As[wm + i * 16 + lm][quad * 8];
      Bf[i] = *(const f16x8*)&Bs[wn + i * 16 + lm][quad * 8];
    }
#pragma unroll
    for (int i = 0; i < 4; ++i)
#pragma unroll
      for (int j = 0; j < 4; ++j)
        acc[i][j] = __builtin_amdgcn_mfma_f32_16x16x32_f16(Af[i], Bf[j], acc[i][j], 0, 0, 0);
  }
#pragma unroll
  for (int i = 0; i < 4; ++i)
#pragma unroll
    for (int j = 0; j < 4; ++j) {
      int col = bn + wn + j * 16 + lm;
#pragma unroll
      for (int r = 0; r < 4; ++r) {
        int row = bm + wm + i * 16 + quad * 4 + r;
        if (row < M && col < N) {
          if (F16OUT)
            ((_Float16*)Cv)[(size_t)row * N + col] = (_Float16)acc[i][j][r];
          else
            ((float*)Cv)[(size_t)row * N + col] = acc[i][j][r];
        }
      }
    }
}

// ---------------------------------------------------------------------------
// FUSED S+P GEMM (R3 structure): global_load_lds staging + 2-phase dbuf
// pipeline with counted vmcnt. WT=1 additionally writes the TRANSPOSED
// q-matrix mhqT[V][K] (fp16): per fragment the 4 r-values are 4 consecutive
// k -> one 8-B store; a wave's 4 quads cover a full 128-B line of mhqT, so
// L2 write-combines (no sustained RFO).
// ---------------------------------------------------------------------------
template <int WT>
__global__ __launch_bounds__(256, 2)
void gemm_sp(const _Float16* __restrict__ Aw, const _Float16* __restrict__ Bw,
             const _Float16* __restrict__ Au, const _Float16* __restrict__ Bu,
             float* __restrict__ Sd, _Float16* __restrict__ mhq,
             _Float16* __restrict__ mhqT,
             const float* __restrict__ AAv, const float* __restrict__ BBv,
             const float* __restrict__ tbias,
             const float* __restrict__ p_log_scale,
             const float* __restrict__ p_log_eps, int M, int N) {
  __shared__ _Float16 As[2][BM][32];   // 2 x 8 KB
  __shared__ _Float16 Bs[2][BM][32];   // 2 x 8 KB
  const int tid = threadIdx.x;
  const int bm = blockIdx.x * BM;   // K-rows: 4 blocks
  const int bn = blockIdx.y * BN;   // V-cols: 393 blocks
  const int wave = tid >> 6;
  const int lane = tid & 63;
  const int wm = (wave >> 1) << 6;
  const int wn = (wave & 1) << 6;
  const int lm = lane & 15;
  const int quad = lane >> 4;

  const int c0 = wave * 2;
  const int r0 = c0 * 16 + (lane >> 2);
  const int r1 = r0 + 16;
  const int gp = lane & 3;
  const int gg0 = gp ^ ((r0 >> 1) & 3);
  const int gg1 = gp ^ ((r1 >> 1) & 3);

  const _Float16* pAu0 = Au + (size_t)(bm + r0) * RR + gg0 * 8;
  const _Float16* pAu1 = Au + (size_t)(bm + r1) * RR + gg1 * 8;
  const _Float16* pBu0 = Bu + (size_t)(bn + r0) * RR + gg0 * 8;
  const _Float16* pBu1 = Bu + (size_t)(bn + r1) * RR + gg1 * 8;
  const _Float16* pAw0 = Aw + (size_t)(bm + r0) * DD + gg0 * 8;
  const _Float16* pAw1 = Aw + (size_t)(bm + r1) * DD + gg1 * 8;
  const _Float16* pBw0 = Bw + (size_t)(bn + r0) * DD + gg0 * 8;
  const _Float16* pBw1 = Bw + (size_t)(bn + r1) * DD + gg1 * 8;

  auto stage = [&](int t, int buf) {
    _Float16* la = &As[buf][0][0] + c0 * 512;
    _Float16* lb = &Bs[buf][0][0] + c0 * 512;
    if (t < 6) {
      int k0 = t * BK;
      gload_lds16(pAu0 + k0, la);
      gload_lds16(pAu1 + k0, la + 512);
      gload_lds16(pBu0 + k0, lb);
      gload_lds16(pBu1 + k0, lb + 512);
    } else {
      int k0 = (t - 6) * BK;
      gload_lds16(pAw0 + k0, la);
      gload_lds16(pAw1 + k0, la + 512);
      gload_lds16(pBw0 + k0, lb);
      gload_lds16(pBw1 + k0, lb + 512);
    }
  };

  f32x4 accP[4][4], accS[4][4];
#pragma unroll
  for (int i = 0; i < 4; ++i)
#pragma unroll
    for (int j = 0; j < 4; ++j) {
      accP[i][j] = (f32x4){0.f, 0.f, 0.f, 0.f};
      accS[i][j] = (f32x4){0.f, 0.f, 0.f, 0.f};
    }

  stage(0, 0);
  for (int t = 0; t < 6; ++t) {
    const int cur = t & 1;
    stage(t + 1, cur ^ 1);
    asm volatile("s_waitcnt vmcnt(4)" ::: "memory");
    __builtin_amdgcn_s_barrier();
    asm volatile("" ::: "memory");
    f16x8 Af[4], Bf[4];
#pragma unroll
    for (int i = 0; i < 4; ++i) {
      int ra_ = wm + i * 16 + lm;
      int rb_ = wn + i * 16 + lm;
      Af[i] = *(const f16x8*)&As[cur][ra_][(quad ^ ((ra_ >> 1) & 3)) * 8];
      Bf[i] = *(const f16x8*)&Bs[cur][rb_][(quad ^ ((rb_ >> 1) & 3)) * 8];
    }
#pragma unroll
    for (int i = 0; i < 4; ++i)
#pragma unroll
      for (int j = 0; j < 4; ++j)
        accP[i][j] = __builtin_amdgcn_mfma_f32_16x16x32_f16(Af[i], Bf[j], accP[i][j], 0, 0, 0);
    asm volatile("" ::: "memory");
    __builtin_amdgcn_s_barrier();
  }
  for (int t = 6; t < 30; ++t) {
    const int cur = t & 1;
    if (t < 29) {
      stage(t + 1, cur ^ 1);
      asm volatile("s_waitcnt vmcnt(4)" ::: "memory");
    } else {
      asm volatile("s_waitcnt vmcnt(0)" ::: "memory");
    }
    __builtin_amdgcn_s_barrier();
    asm volatile("" ::: "memory");
    f16x8 Af[4], Bf[4];
#pragma unroll
    for (int i = 0; i < 4; ++i) {
      int ra_ = wm + i * 16 + lm;
      int rb_ = wn + i * 16 + lm;
      Af[i] = *(const f16x8*)&As[cur][ra_][(quad ^ ((ra_ >> 1) & 3)) * 8];
      Bf[i] = *(const f16x8*)&Bs[cur][rb_][(quad ^ ((rb_ >> 1) & 3)) * 8];
    }
#pragma unroll
    for (int i = 0; i < 4; ++i)
#pragma unroll
      for (int j = 0; j < 4; ++j)
        accS[i][j] = __builtin_amdgcn_mfma_f32_16x16x32_f16(Af[i], Bf[j], accS[i][j], 0, 0, 0);
    asm volatile("" ::: "memory");
    __builtin_amdgcn_s_barrier();
  }

  float scale = fminf(expf(p_log_scale[0]), 20.f);
  float qs = L2E / get_eps(p_log_eps);
#pragma unroll
  for (int i = 0; i < 4; ++i)
#pragma unroll
    for (int j = 0; j < 4; ++j) {
      int col = bn + wn + j * 16 + lm;
      if (col >= N) continue;
      float BB = BBv[col];
      f16x4 tq;
#pragma unroll
      for (int r = 0; r < 4; ++r) {
        int row = bm + wm + i * 16 + quad * 4 + r;
        float S = accS[i][j][r];
        float mh = fmaxf(AAv[row] + BB - 2.f * (S + accP[i][j][r]), 0.f);
        Sd[(size_t)row * N + col] = fmaf(scale, S, tbias[row]);
        _Float16 q = (_Float16)(mh * qs);
        mhq[(size_t)row * VP + col] = q;
        tq[r] = q;
      }
      if (WT)
        *(f16x4*)(mhqT + (size_t)col * KK + (bm + wm + i * 16 + quad * 4)) = tq;
    }
}

// ---------------------------------------------------------------------------
// P-GEMM + fused epilogue (tight-workspace fallback)
// ---------------------------------------------------------------------------
__global__ __launch_bounds__(256, 2)
void gemm16_p(const _Float16* __restrict__ A, const _Float16* __restrict__ B,
              float* __restrict__ Sd, _Float16* __restrict__ mhq,
              const float* __restrict__ AAv, const float* __restrict__ BBv,
              const float* __restrict__ tbias,
              const float* __restrict__ p_log_scale,
              const float* __restrict__ p_log_eps, int M, int N, int Kd) {
  __shared__ _Float16 As[BM][LDK];
  __shared__ _Float16 Bs[BN][LDK];
  const int tid = threadIdx.x;
  const int bm = blockIdx.y * BM;
  const int bn = blockIdx.x * BN;
  const int srow = tid >> 1;
  const int skb = (tid & 1) << 4;
  const int wave = tid >> 6;
  const int lane = tid & 63;
  const int wm = (wave >> 1) << 6;
  const int wn = (wave & 1) << 6;
  const int lm = lane & 15;
  const int quad = lane >> 4;
  f32x4 acc[4][4];
#pragma unroll
  for (int i = 0; i < 4; ++i)
#pragma unroll
    for (int j = 0; j < 4; ++j) acc[i][j] = (f32x4){0.f, 0.f, 0.f, 0.f};
  const int ra = bm + srow;
  const int rb = bn + srow;
  for (int k0 = 0; k0 < Kd; k0 += BK) {
    f16x8 a0 = (f16x8)(_Float16)0, a1 = a0, b0 = a0, b1 = a0;
    if (ra < M) {
      const f16x8* p = (const f16x8*)(A + (size_t)ra * Kd + k0 + skb);
      a0 = p[0]; a1 = p[1];
    }
    if (rb < N) {
      const f16x8* p = (const f16x8*)(B + (size_t)rb * Kd + k0 + skb);
      b0 = p[0]; b1 = p[1];
    }
    __syncthreads();
    *(f16x8*)&As[srow][skb] = a0; *(f16x8*)&As[srow][skb + 8] = a1;
    *(f16x8*)&Bs[srow][skb] = b0; *(f16x8*)&Bs[srow][skb + 8] = b1;
    __syncthreads();
    f16x8 Af[4], Bf[4];
#pragma unroll
    for (int i = 0; i < 4; ++i) {
      Af[i] = *(const f16x8*)&As[wm + i * 16 + lm][quad * 8];
      Bf[i] = *(const f16x8*)&Bs[wn + i * 16 + lm][quad * 8];
    }
#pragma unroll
    for (int i = 0; i < 4; ++i)
#pragma unroll
      for (int j = 0; j < 4; ++j)
        acc[i][j] = __builtin_amdgcn_mfma_f32_16x16x32_f16(Af[i], Bf[j], acc[i][j], 0, 0, 0);
  }
  float scale = fminf(expf(p_log_scale[0]), 20.f);
  float qs = L2E / get_eps(p_log_eps);
#pragma unroll
  for (int i = 0; i < 4; ++i)
#pragma unroll
    for (int j = 0; j < 4; ++j) {
      int col = bn + wn + j * 16 + lm;
      if (col >= N) continue;
      float BB = BBv[col];
#pragma unroll
      for (int r = 0; r < 4; ++r) {
        int row = bm + wm + i * 16 + quad * 4 + r;
        size_t idx = (size_t)row * N + col;
        float S = Sd[idx];
        float mh = fmaxf(AAv[row] + BB - 2.f * (S + acc[i][j][r]), 0.f);
        Sd[idx] = fmaf(scale, S, tbias[row]);
        mhq[(size_t)row * VP + col] = (_Float16)(mh * qs);
      }
    }
}

// ---------------------------------------------------------------------------
// out[r] = 1 + sum(X16[r,:]^2), cols <= 256
// ---------------------------------------------------------------------------
__global__ __launch_bounds__(256)
void row_sumsq16(const _Float16* __restrict__ X, float* __restrict__ out, int cols) {
  int r = blockIdx.x;
  int t = threadIdx.x;
  float x = (t < cols) ? (float)X[(size_t)r * cols + t] : 0.f;
  __shared__ float red[256];
  red[t] = x * x;
  __syncthreads();
  for (int off = 128; off > 0; off >>= 1) {
    if (t < off) red[t] += red[t + off];
    __syncthreads();
  }
  if (t == 0) out[r] = 1.0f + red[0];
}

// ---------------------------------------------------------------------------
// Sinkhorn row (log2 domain): lu2[k] = -(Mv2 + log2(sum_v 2^(lv2[v]-Mv2-q)))
// ---------------------------------------------------------------------------
__global__ __launch_bounds__(1024)
void sink_row(const _Float16* __restrict__ mhq, const float* __restrict__ lv2,
              float* __restrict__ lu2,
              const unsigned* __restrict__ Mv_slot, unsigned* __restrict__ Mu_slot) {
  int k = blockIdx.x;
  int t = threadIdx.x;
  float Mv2 = dec_f(*Mv_slot);
  const _Float16* row = mhq + (size_t)k * VP;
  float s[8] = {0.f, 0.f, 0.f, 0.f, 0.f, 0.f, 0.f, 0.f};
#pragma unroll
  for (int j = 0; j < 6; ++j) {
    int v = j * 8192 + t * 8;
    f16x8 hv = *(const f16x8*)(row + v);
    float4 l0 = *(const float4*)(lv2 + v);
    float4 l1 = *(const float4*)(lv2 + v + 4);
    float lv[8] = {l0.x, l0.y, l0.z, l0.w, l1.x, l1.y, l1.z, l1.w};
#pragma unroll
    for (int i = 0; i < 8; ++i)
      s[i] += fast_exp2(lv[i] - Mv2 - (float)hv[i]);
  }
  {
    int v = 49152 + t;
    s[0] += fast_exp2(lv2[v] - Mv2 - (float)row[v]);
    v = 50176 + t;
    if (v < VV) s[1] += fast_exp2(lv2[v] - Mv2 - (float)row[v]);
  }
  float sum = ((s[0] + s[1]) + (s[2] + s[3])) + ((s[4] + s[5]) + (s[6] + s[7]));
  __shared__ float red[1024];
  red[t] = sum;
  __syncthreads();
  for (int off = 512; off > 0; off >>= 1) {
    if (t < off) red[t] += red[t + off];
    __syncthreads();
  }
  if (t == 0) {
    float lu = -(Mv2 + log2f(red[0]));
    lu2[k] = lu;
    atomicMax(Mu_slot, enc_f(lu));
  }
}

// ---------------------------------------------------------------------------
// Sinkhorn col over the TRANSPOSED q-matrix: one wave per v, one f16x8 per
// lane covers all 512 k (fully coalesced 1 KB row). 16 v per block.
//   lv2[v] = -(Mu2 + log2(sum_k 2^(lu2[k]-Mu2-q[k,v])))
// ---------------------------------------------------------------------------
__global__ __launch_bounds__(1024)
void sink_colT(const _Float16* __restrict__ mhqT, const float* __restrict__ lu2,
               float* __restrict__ lv2,
               const unsigned* __restrict__ Mu_slot, unsigned* __restrict__ Mv_next) {
  __shared__ float lum[KK];
  __shared__ float wmax[16];
  int t = threadIdx.x;
  float Mu2 = dec_f(*Mu_slot);
  if (t < KK) lum[t] = lu2[t] - Mu2;
  __syncthreads();
  int wave = t >> 6;
  int lane = t & 63;
  int v = blockIdx.x * 16 + wave;
  float lv = -1e38f;
  if (v < VV) {
    f16x8 hv = *(const f16x8*)(mhqT + (size_t)v * KK + lane * 8);
    const float* lp = &lum[lane * 8];
    float s = 0.f;
#pragma unroll
    for (int j = 0; j < 8; ++j) s += fast_exp2(lp[j] - (float)hv[j]);
#pragma unroll
    for (int off = 32; off > 0; off >>= 1) s += __shfl_xor(s, off);
    lv = -(Mu2 + log2f(s));
    if (lane == 0) lv2[v] = lv;
  }
  if (lane == 0) wmax[wave] = lv;
  __syncthreads();
  if (t == 0) {
    float m = wmax[0];
#pragma unroll
    for (int w = 1; w < 16; ++w) m = fmaxf(m, wmax[w]);
    atomicMax(Mv_next, enc_f(m));
  }
}

// ---------------------------------------------------------------------------
// Sinkhorn col (legacy, strided mhq; used when mhqT doesn't fit)
// ---------------------------------------------------------------------------
__global__ __launch_bounds__(256)
void sink_col(const _Float16* __restrict__ mhq, const float* __restrict__ lu2,
              float* __restrict__ lv2,
              const unsigned* __restrict__ Mu_slot, unsigned* __restrict__ Mv_next) {
  __shared__ float lu_s[KK];
  int t = threadIdx.x;
  for (int i = t; i < KK; i += 256) lu_s[i] = lu2[i];
  __syncthreads();
  float Mu2 = dec_f(*Mu_slot);
  int cp = blockIdx.x * 64 + (t & 63);
  int v0 = cp * 2;
  int kc = t >> 6;
  float sA = 0.f, sB = 0.f;
  if (v0 < VV) {
    const _Float16* base = mhq + v0;
#pragma unroll 4
    for (int k = kc * 128; k < kc * 128 + 128; ++k) {
      f16x2 hv = *(const f16x2*)(base + (size_t)k * VP);
      float lu = lu_s[k] - Mu2;
      sA += fast_exp2(lu - (float)hv[0]);
      sB += fast_exp2(lu - (float)hv[1]);
    }
  }
  __shared__ float pA[256], pB[256];
  __shared__ unsigned em[64];
  pA[t] = sA; pB[t] = sB;
  __syncthreads();
  if (t < 64) {
    unsigned e = ENC_NEG_INF;
    if (v0 < VV) {
      float a = (pA[t] + pA[t + 64]) + (pA[t + 128] + pA[t + 192]);
      float lv = -(Mu2 + log2f(a));
      lv2[v0] = lv;
      e = enc_f(lv);
      if (v0 + 1 < VV) {
        float b = (pB[t] + pB[t + 64]) + (pB[t + 128] + pB[t + 192]);
        float lv1 = -(Mu2 + log2f(b));
        lv2[v0 + 1] = lv1;
        unsigned e1 = enc_f(lv1);
        if (e1 > e) e = e1;
      }
    }
    em[t] = e;
  }
  __syncthreads();
  for (int off = 32; off > 0; off >>= 1) {
    if (t < off && em[t + off] > em[t]) em[t] = em[t + off];
    __syncthreads();
  }
  if (t == 0) atomicMax(Mv_next, em[0]);
}

// ---------------------------------------------------------------------------
// final pass 1: row_s[k] = sum_v exp(logit - 30)   (logits clipped at +-30)
// ---------------------------------------------------------------------------
__global__ __launch_bounds__(1024)
void final_sum(const float* __restrict__ direct, const _Float16* __restrict__ mhq,
               const float* __restrict__ lu2, const float* __restrict__ lv2,
               float* __restrict__ row_s, const float* __restrict__ p_log_eps) {
  int k = blockIdx.x;
  int t = threadIdx.x;
  float eps = get_eps(p_log_eps);
  float c2 = (LAM * eps + GAM) / L2E;
  float c3 = GAM / L2E;
  float base_lu = c3 * lu2[k];
  const float* drow = direct + (size_t)k * VV;
  const _Float16* mrow = mhq + (size_t)k * VP;
  float s[8] = {0.f, 0.f, 0.f, 0.f, 0.f, 0.f, 0.f, 0.f};
#pragma unroll
  for (int j = 0; j < 6; ++j) {
    int v = j * 8192 + t * 8;
    f16x8 hv = *(const f16x8*)(mrow + v);
    float4 d0 = *(const float4*)(drow + v);
    float4 d1 = *(const float4*)(drow + v + 4);
    float4 l0 = *(const float4*)(lv2 + v);
    float4 l1 = *(const float4*)(lv2 + v + 4);
    float dd[8] = {d0.x, d0.y, d0.z, d0.w, d1.x, d1.y, d1.z, d1.w};
    float lv[8] = {l0.x, l0.y, l0.z, l0.w, l1.x, l1.y, l1.z, l1.w};
#pragma unroll
    for (int i = 0; i < 8; ++i) {
      float x = fmaf(-c2, (float)hv[i], fmaf(c3, lv[i], dd[i] + base_lu));
      x = fminf(30.f, fmaxf(-30.f, x));
      s[i] += fast_exp2(fmaf(x, L2E, -30.f * L2E));
    }
  }
  {
    int v = 49152 + t;
    float x = fmaf(-c2, (float)mrow[v], fmaf(c3, lv2[v], drow[v] + base_lu));
    x = fminf(30.f, fmaxf(-30.f, x));
    s[0] += fast_exp2(fmaf(x, L2E, -30.f * L2E));
    v = 50176 + t;
    if (v < VV) {
      x = fmaf(-c2, (float)mrow[v], fmaf(c3, lv2[v], drow[v] + base_lu));
      x = fminf(30.f, fmaxf(-30.f, x));
      s[1] += fast_exp2(fmaf(x, L2E, -30.f * L2E));
    }
  }
  float sum = ((s[0] + s[1]) + (s[2] + s[3])) + ((s[4] + s[5]) + (s[6] + s[7]));
  __shared__ float red[1024];
  red[t] = sum;
  __syncthreads();
  for (int off = 512; off > 0; off >>= 1) {
    if (t < off) red[t] += red[t + off];
    __syncthreads();
  }
  if (t == 0) row_s[k] = red[0];
}

// ---------------------------------------------------------------------------
// final pass 2: out[k,v] = exp(logit - 30) / row_s[k]
// ---------------------------------------------------------------------------
__global__ __launch_bounds__(256)
void final_write(float* __restrict__ out, const _Float16* __restrict__ mhq,
                 const float* __restrict__ lu2, const float* __restrict__ lv2,
                 const float* __restrict__ row_s, const float* __restrict__ p_log_eps) {
  int v = blockIdx.x * 256 + threadIdx.x;
  int k = blockIdx.y;
  if (v >= VV) return;
  float eps = get_eps(p_log_eps);
  float c2 = (LAM * eps + GAM) / L2E;
  float c3 = GAM / L2E;
  size_t idx = (size_t)k * VV + v;
  float x = fmaf(-c2, (float)mhq[(size_t)k * VP + v],
                 fmaf(c3, lv2[v], out[idx] + c3 * lu2[k]));
  x = fminf(30.f, fmaxf(-30.f, x));
  out[idx] = fast_exp2(fmaf(x, L2E, -30.f * L2E)) / row_s[k];
}

// ---------------------------------------------------------------------------
// launch
// ---------------------------------------------------------------------------
extern "C" void kernel_launch(void* const* d_in, const int* in_sizes, int n_in,
                              void* d_out, int out_size, void* d_ws, size_t ws_size,
                              hipStream_t stream) {
  (void)in_sizes; (void)n_in; (void)out_size;
  const float* WE        = (const float*)d_in[0];
  const float* anchors   = (const float*)d_in[1];
  const float* MU        = (const float*)d_in[2];
  const float* log_eps   = (const float*)d_in[3];
  const float* log_scale = (const float*)d_in[4];
  const float* tbias     = (const float*)d_in[5];
  const float* Wp        = (const float*)d_in[6];
  float* out = (float*)d_out;

  const size_t H_W16 = (size_t)VV * DD;   // 38,597,376 halfs
  const size_t H_MHQ = (size_t)KK * VP;   // 25,739,264 halfs
  const size_t H_MHT = (size_t)VV * KK;   // 25,731,584 halfs
  const size_t H_WU  = (size_t)VV * RR;
  const size_t H_A16 = (size_t)KK * DD;
  const size_t H_AU  = (size_t)KK * RR;
  const size_t H_UT  = (size_t)RR * DD;
  const size_t FB_FLOATS = 102064 + 32;   // fp32 region incl. slots
  const size_t need_roomy =
      2 * (H_W16 + H_MHQ + H_WU + H_A16 + H_AU + H_UT) + 4 * FB_FLOATS;
  const size_t need_roomy2 = need_roomy + 2 * H_MHT;
  const bool roomy2 = ws_size >= need_roomy2;
  const bool roomy = ws_size >= need_roomy;

  _Float16* hb = (_Float16*)d_ws;
  _Float16* w16 = hb;
  size_t ho = H_W16;
  _Float16* mhq;
  if (roomy) { mhq = hb + ho; ho += H_MHQ; }
  else       { mhq = hb; }                 // alias w16 (dead after S GEMM)
  _Float16* mhqT = hb + ho;
  if (roomy2) ho += H_MHT;
  _Float16* wU16 = hb + ho; ho += H_WU;
  _Float16* a16  = hb + ho; ho += H_A16;
  _Float16* aU16 = hb + ho; ho += H_AU;
  _Float16* Ut16 = hb + ho; ho += H_UT;
  float* fb = (float*)(hb + ho);
  float* BBv   = fb;           // 50264
  float* AAv   = fb + 50264;   // 512
  float* lu2   = fb + 50776;   // 512
  float* lv2   = fb + 51288;   // 50264
  float* row_s = fb + 101552;  // 512
  unsigned* slots = (unsigned*)(fb + 102064);  // 25
  unsigned* Mv_slots = slots;
  unsigned* Mu_slots = slots + 12;
  unsigned* eye_flag = slots + 24;

  const int VB = (VV + 255) / 256;      // 197
  const int MB_V = (VV + BM - 1) / BM;  // 393
  const int NBT = (VV + 15) / 16;       // 3142 (one wave per v)

  prep<<<1286, 256, 0, stream>>>(MU, lv2, slots, anchors, Ut16, a16);
  check_eye<<<(DD * DD + 255) / 256, 256, 0, stream>>>(Wp, eye_flag);
  gemm_we_fallback<<<dim3(DD / BN, MB_V), 256, 0, stream>>>(WE, Wp, w16, VV, DD, DD, eye_flag);
  norm_w<<<VV, 256, 0, stream>>>(WE, w16, eye_flag);
  gemm16<1><<<dim3(2, MB_V), 256, 0, stream>>>(w16, Ut16, wU16, VV, RR, DD);
  gemm16<1><<<dim3(2, 4), 256, 0, stream>>>(a16, Ut16, aU16, KK, RR, DD);
  row_sumsq16<<<VV, 256, 0, stream>>>(wU16, BBv, RR);
  row_sumsq16<<<KK, 256, 0, stream>>>(aU16, AAv, RR);
  if (roomy2) {
    gemm_sp<1><<<dim3(4, MB_V), 256, 0, stream>>>(a16, w16, aU16, wU16, out, mhq,
                                                  mhqT, AAv, BBv, tbias, log_scale,
                                                  log_eps, KK, VV);
    for (int it = 0; it < 10; ++it) {
      sink_row<<<KK, 1024, 0, stream>>>(mhq, lv2, lu2, Mv_slots + it, Mu_slots + it);
      sink_colT<<<NBT, 1024, 0, stream>>>(mhqT, lu2, lv2, Mu_slots + it, Mv_slots + it + 1);
    }
  } else if (roomy) {
    gemm_sp<0><<<dim3(4, MB_V), 256, 0, stream>>>(a16, w16, aU16, wU16, out, mhq,
                                                  mhqT, AAv, BBv, tbias, log_scale,
                                                  log_eps, KK, VV);
    for (int it = 0; it < 10; ++it) {
      sink_row<<<KK, 1024, 0, stream>>>(mhq, lv2, lu2, Mv_slots + it, Mu_slots + it);
      sink_col<<<MB_V, 256, 0, stream>>>(mhq, lu2, lv2, Mu_slots + it, Mv_slots + it + 1);
    }
  } else {
    gemm16<0><<<dim3(MB_V, 4), 256, 0, stream>>>(a16, w16, out, KK, VV, DD);
    gemm16_p<<<dim3(MB_V, 4), 256, 0, stream>>>(aU16, wU16, out, mhq, AAv, BBv,
                                                tbias, log_scale, log_eps, KK, VV, RR);
    for (int it = 0; it < 10; ++it) {
      sink_row<<<KK, 1024, 0, stream>>>(mhq, lv2, lu2, Mv_slots + it, Mu_slots + it);
      sink_col<<<MB_V, 256, 0, stream>>>(mhq, lu2, lv2, Mu_slots + it, Mv_slots + it + 1);
    }
  }
  final_sum<<<KK, 1024, 0, stream>>>(out, mhq, lu2, lv2, row_s, log_eps);
  final_write<<<dim3(VB, KK), 256, 0, stream>>>(out, mhq, lu2, lv2, row_s, log_eps);
}

// Round 6
// 1030.571 us; speedup vs baseline: 2.6699x; 1.1202x over previous
//
#include <hip/hip_runtime.h>
#include <math.h>

#define KK 512
#define VV 50257
#define VP 50272   // padded mhq row stride (halfs)
#define DD 768
#define RR 192

#define LAM 0.3f
#define GAM 0.3f
#define L2E 1.44269504088896340736f

typedef __bf16 bf16x8 __attribute__((ext_vector_type(8)));
typedef _Float16 f16x8 __attribute__((ext_vector_type(8)));
typedef unsigned short u16x8 __attribute__((ext_vector_type(8)));
typedef float f32x4 __attribute__((ext_vector_type(4)));

// ---------------------------------------------------------------------------
// helpers
// ---------------------------------------------------------------------------
static __device__ __forceinline__ float get_eps(const float* p_log_eps) {
  return log1pf(expf(p_log_eps[0])) + 0.001f;  // softplus(log_eps)+1e-3
}

static __device__ __forceinline__ float fast_exp2(float x) {
  return __builtin_amdgcn_exp2f(x);  // v_exp_f32 (2^x)
}

// fp32 -> bf16 rne (for the non-eye fallback GEMM only)
static __device__ __forceinline__ unsigned short f2bf(float x) {
  unsigned u = __builtin_bit_cast(unsigned, x);
  u += 0x7fffu + ((u >> 16) & 1u);
  return (unsigned short)(u >> 16);
}
static __device__ __forceinline__ float bf2f(unsigned short h) {
  unsigned u = ((unsigned)h) << 16;
  return __builtin_bit_cast(float, u);
}

// async global->LDS DMA, 16 B per lane. LDS dest is wave-uniform base +
// lane*16 (m104); global src is per-lane.
static __device__ __forceinline__ void gload_lds16(const void* g, void* l) {
  __builtin_amdgcn_global_load_lds(
      (const __attribute__((address_space(1))) unsigned int*)g,
      (__attribute__((address_space(3))) unsigned int*)l, 16, 0, 0);
}

// ---------------------------------------------------------------------------
// prep: fused small-kernel pass.
//  blocks [0,576):    Ut16[r,d] = fp16(U[d,r])
//  blocks [576,598):  Rbuf[11][512] = 0 (sinkhorn row-sum accumulators)
//  block 598:         eye flag init
//  blocks [599,1111): a16 = fp16(normalize(anchors)), one block per row
// ---------------------------------------------------------------------------
__global__ __launch_bounds__(256)
void prep(const float* __restrict__ U, unsigned* __restrict__ slots,
          const float* __restrict__ anchors,
          _Float16* __restrict__ Ut16, _Float16* __restrict__ a16,
          float* __restrict__ Rbuf) {
  int bid = blockIdx.x;
  int t = threadIdx.x;
  if (bid < 576) {
    int idx = bid * 256 + t;
    int r = idx / DD;
    int d = idx - r * DD;
    Ut16[idx] = (_Float16)U[(size_t)d * RR + r];
  } else if (bid < 598) {
    int i = (bid - 576) * 256 + t;
    if (i < 11 * KK) Rbuf[i] = 0.f;
  } else if (bid == 598) {
    if (t == 0) slots[24] = 1u;  // eye_flag
  } else {
    int r = bid - 599;
    const float* x = anchors + (size_t)r * DD;
    float v0 = x[t], v1 = x[t + 256], v2 = x[t + 512];
    __shared__ float red[256];
    red[t] = v0 * v0 + v1 * v1 + v2 * v2;
    __syncthreads();
    for (int off = 128; off > 0; off >>= 1) {
      if (t < off) red[t] += red[t + off];
      __syncthreads();
    }
    float inv = 1.0f / fmaxf(sqrtf(red[0]), 1e-12f);
    _Float16* y = a16 + (size_t)r * DD;
    y[t] = (_Float16)(v0 * inv);
    y[t + 256] = (_Float16)(v1 * inv);
    y[t + 512] = (_Float16)(v2 * inv);
  }
}

// ---------------------------------------------------------------------------
// check Wp == I (exact); clears eye flag on mismatch
// ---------------------------------------------------------------------------
__global__ __launch_bounds__(256)
void check_eye(const float* __restrict__ Wp, unsigned* __restrict__ flag) {
  int i = blockIdx.x * 256 + threadIdx.x;
  if (i >= DD * DD) return;
  int r = i / DD;
  int c = i - r * DD;
  float expect = (r == c) ? 1.f : 0.f;
  if (Wp[i] != expect) atomicAnd(flag, 0u);
}

// ---------------------------------------------------------------------------
// FALLBACK ONLY (Wp != I): split-bf16 3-term GEMM w_raw = WE @ Wp^T -> fp16.
// ---------------------------------------------------------------------------
#define BM 128
#define BN 128
#define BK 32
#define LDKB 40  // bf16 fallback LDS stride
#define LDK 40   // fp16 LDS stride (pad -> 2-way banks, free)

__global__ __launch_bounds__(256, 2)
void gemm_we_fallback(const float* __restrict__ A, const float* __restrict__ B,
                      _Float16* __restrict__ C, int M, int N, int Kd,
                      const unsigned* __restrict__ eyeflag) {
  if (*eyeflag) return;
  __shared__ unsigned short As[2][BM][LDKB];
  __shared__ unsigned short Bs[2][BN][LDKB];
  const int tid = threadIdx.x;
  const int bm = blockIdx.y * BM;
  const int bn = blockIdx.x * BN;
  const int srow = tid >> 1;
  const int skb = (tid & 1) << 4;
  const int wave = tid >> 6;
  const int lane = tid & 63;
  const int wm = (wave >> 1) << 6;
  const int wn = (wave & 1) << 6;
  const int lm = lane & 15;
  const int quad = lane >> 4;
  f32x4 acc[4][4];
#pragma unroll
  for (int i = 0; i < 4; ++i)
#pragma unroll
    for (int j = 0; j < 4; ++j) acc[i][j] = (f32x4){0.f, 0.f, 0.f, 0.f};
  const int ra = bm + srow;
  const int rb = bn + srow;
  for (int k0 = 0; k0 < Kd; k0 += BK) {
    float va[16], vb[16];
    if (ra < M) {
      const float4* p = (const float4*)(A + (size_t)ra * Kd + k0 + skb);
      ((float4*)va)[0] = p[0]; ((float4*)va)[1] = p[1];
      ((float4*)va)[2] = p[2]; ((float4*)va)[3] = p[3];
    } else {
#pragma unroll
      for (int q = 0; q < 16; ++q) va[q] = 0.f;
    }
    if (rb < N) {
      const float4* p = (const float4*)(B + (size_t)rb * Kd + k0 + skb);
      ((float4*)vb)[0] = p[0]; ((float4*)vb)[1] = p[1];
      ((float4*)vb)[2] = p[2]; ((float4*)vb)[3] = p[3];
    } else {
#pragma unroll
      for (int q = 0; q < 16; ++q) vb[q] = 0.f;
    }
    __syncthreads();
    {
      u16x8 h0, h1, l0, l1;
#pragma unroll
      for (int q = 0; q < 8; ++q) {
        unsigned short h = f2bf(va[q]);
        h0[q] = h; l0[q] = f2bf(va[q] - bf2f(h));
        h = f2bf(va[q + 8]);
        h1[q] = h; l1[q] = f2bf(va[q + 8] - bf2f(h));
      }
      *(u16x8*)&As[0][srow][skb] = h0; *(u16x8*)&As[0][srow][skb + 8] = h1;
      *(u16x8*)&As[1][srow][skb] = l0; *(u16x8*)&As[1][srow][skb + 8] = l1;
#pragma unroll
      for (int q = 0; q < 8; ++q) {
        unsigned short h = f2bf(vb[q]);
        h0[q] = h; l0[q] = f2bf(vb[q] - bf2f(h));
        h = f2bf(vb[q + 8]);
        h1[q] = h; l1[q] = f2bf(vb[q + 8] - bf2f(h));
      }
      *(u16x8*)&Bs[0][srow][skb] = h0; *(u16x8*)&Bs[0][srow][skb + 8] = h1;
      *(u16x8*)&Bs[1][srow][skb] = l0; *(u16x8*)&Bs[1][srow][skb + 8] = l1;
    }
    __syncthreads();
    bf16x8 Ah[4], Al[4], Bh[4], Bl[4];
#pragma unroll
    for (int i = 0; i < 4; ++i) {
      Ah[i] = *(const bf16x8*)&As[0][wm + i * 16 + lm][quad * 8];
      Al[i] = *(const bf16x8*)&As[1][wm + i * 16 + lm][quad * 8];
      Bh[i] = *(const bf16x8*)&Bs[0][wn + i * 16 + lm][quad * 8];
      Bl[i] = *(const bf16x8*)&Bs[1][wn + i * 16 + lm][quad * 8];
    }
#pragma unroll
    for (int i = 0; i < 4; ++i)
#pragma unroll
      for (int j = 0; j < 4; ++j) {
        acc[i][j] = __builtin_amdgcn_mfma_f32_16x16x32_bf16(Ah[i], Bh[j], acc[i][j], 0, 0, 0);
        acc[i][j] = __builtin_amdgcn_mfma_f32_16x16x32_bf16(Ah[i], Bl[j], acc[i][j], 0, 0, 0);
        acc[i][j] = __builtin_amdgcn_mfma_f32_16x16x32_bf16(Al[i], Bh[j], acc[i][j], 0, 0, 0);
      }
  }
#pragma unroll
  for (int i = 0; i < 4; ++i)
#pragma unroll
    for (int j = 0; j < 4; ++j) {
      int col = bn + wn + j * 16 + lm;
#pragma unroll
      for (int r = 0; r < 4; ++r) {
        int row = bm + wm + i * 16 + quad * 4 + r;
        if (row < M && col < N) C[(size_t)row * N + col] = (_Float16)acc[i][j][r];
      }
    }
}

// ---------------------------------------------------------------------------
// norm_w: w16[r,:] = fp16(normalize(src[r,:])), src = eye ? WE(f32) : w16(f16)
// ---------------------------------------------------------------------------
__global__ __launch_bounds__(256)
void norm_w(const float* __restrict__ WE, _Float16* __restrict__ w16,
            const unsigned* __restrict__ eyeflag) {
  int r = blockIdx.x;
  int t = threadIdx.x;
  float v0, v1, v2;
  if (*eyeflag) {
    const float* x = WE + (size_t)r * DD;
    v0 = x[t]; v1 = x[t + 256]; v2 = x[t + 512];
  } else {
    const _Float16* x = w16 + (size_t)r * DD;
    v0 = (float)x[t]; v1 = (float)x[t + 256]; v2 = (float)x[t + 512];
  }
  __shared__ float red[256];
  red[t] = v0 * v0 + v1 * v1 + v2 * v2;
  __syncthreads();
  for (int off = 128; off > 0; off >>= 1) {
    if (t < off) red[t] += red[t + off];
    __syncthreads();
  }
  float inv = 1.0f / fmaxf(sqrtf(red[0]), 1e-12f);
  _Float16* y = w16 + (size_t)r * DD;
  y[t] = (_Float16)(v0 * inv);
  y[t + 256] = (_Float16)(v1 * inv);
  y[t + 512] = (_Float16)(v2 * inv);
}

// ---------------------------------------------------------------------------
// fp16 single-term MFMA GEMM: C[M,N] = A[M,Kd]*B[N,Kd]^T. 128x128 tile, BK=32.
// ---------------------------------------------------------------------------
template <int F16OUT>
__global__ __launch_bounds__(256, 2)
void gemm16(const _Float16* __restrict__ A, const _Float16* __restrict__ B,
            void* __restrict__ Cv, int M, int N, int Kd) {
  __shared__ _Float16 As[BM][LDK];
  __shared__ _Float16 Bs[BN][LDK];
  const int tid = threadIdx.x;
  const int bm = blockIdx.y * BM;
  const int bn = blockIdx.x * BN;
  const int srow = tid >> 1;
  const int skb = (tid & 1) << 4;
  const int wave = tid >> 6;
  const int lane = tid & 63;
  const int wm = (wave >> 1) << 6;
  const int wn = (wave & 1) << 6;
  const int lm = lane & 15;
  const int quad = lane >> 4;
  f32x4 acc[4][4];
#pragma unroll
  for (int i = 0; i < 4; ++i)
#pragma unroll
    for (int j = 0; j < 4; ++j) acc[i][j] = (f32x4){0.f, 0.f, 0.f, 0.f};
  const int ra = bm + srow;
  const int rb = bn + srow;
  for (int k0 = 0; k0 < Kd; k0 += BK) {
    f16x8 a0 = (f16x8)(_Float16)0, a1 = a0, b0 = a0, b1 = a0;
    if (ra < M) {
      const f16x8* p = (const f16x8*)(A + (size_t)ra * Kd + k0 + skb);
      a0 = p[0]; a1 = p[1];
    }
    if (rb < N) {
      const f16x8* p = (const f16x8*)(B + (size_t)rb * Kd + k0 + skb);
      b0 = p[0]; b1 = p[1];
    }
    __syncthreads();
    *(f16x8*)&As[srow][skb] = a0; *(f16x8*)&As[srow][skb + 8] = a1;
    *(f16x8*)&Bs[srow][skb] = b0; *(f16x8*)&Bs[srow][skb + 8] = b1;
    __syncthreads();
    f16x8 Af[4], Bf[4];
#pragma unroll
    for (int i = 0; i < 4; ++i) {
      Af[i] = *(const f16x8*)&As[wm + i * 16 + lm][quad * 8];
      Bf[i] = *(const f16x8*)&Bs[wn + i * 16 + lm][quad * 8];
    }
#pragma unroll
    for (int i = 0; i < 4; ++i)
#pragma unroll
      for (int j = 0; j < 4; ++j)
        acc[i][j] = __builtin_amdgcn_mfma_f32_16x16x32_f16(Af[i], Bf[j], acc[i][j], 0, 0, 0);
  }
#pragma unroll
  for (int i = 0; i < 4; ++i)
#pragma unroll
    for (int j = 0; j < 4; ++j) {
      int col = bn + wn + j * 16 + lm;
#pragma unroll
      for (int r = 0; r < 4; ++r) {
        int row = bm + wm + i * 16 + quad * 4 + r;
        if (row < M && col < N) {
          if (F16OUT)
            ((_Float16*)Cv)[(size_t)row * N + col] = (_Float16)acc[i][j][r];
          else
            ((float*)Cv)[(size_t)row * N + col] = acc[i][j][r];
        }
      }
    }
}

// ---------------------------------------------------------------------------
// FUSED S+P GEMM (R3 structure, 120us): global_load_lds staging + 2-phase
// dbuf pipeline with counted vmcnt.
// ---------------------------------------------------------------------------
__global__ __launch_bounds__(256, 2)
void gemm_sp(const _Float16* __restrict__ Aw, const _Float16* __restrict__ Bw,
             const _Float16* __restrict__ Au, const _Float16* __restrict__ Bu,
             float* __restrict__ Sd, _Float16* __restrict__ mhq,
             const float* __restrict__ AAv, const float* __restrict__ BBv,
             const float* __restrict__ tbias,
             const float* __restrict__ p_log_scale,
             const float* __restrict__ p_log_eps, int M, int N) {
  __shared__ _Float16 As[2][BM][32];   // 2 x 8 KB
  __shared__ _Float16 Bs[2][BM][32];   // 2 x 8 KB
  const int tid = threadIdx.x;
  const int bm = blockIdx.x * BM;   // K-rows: 4 blocks
  const int bn = blockIdx.y * BN;   // V-cols: 393 blocks
  const int wave = tid >> 6;
  const int lane = tid & 63;
  const int wm = (wave >> 1) << 6;
  const int wn = (wave & 1) << 6;
  const int lm = lane & 15;
  const int quad = lane >> 4;

  const int c0 = wave * 2;
  const int r0 = c0 * 16 + (lane >> 2);
  const int r1 = r0 + 16;
  const int gp = lane & 3;
  const int gg0 = gp ^ ((r0 >> 1) & 3);
  const int gg1 = gp ^ ((r1 >> 1) & 3);

  const _Float16* pAu0 = Au + (size_t)(bm + r0) * RR + gg0 * 8;
  const _Float16* pAu1 = Au + (size_t)(bm + r1) * RR + gg1 * 8;
  const _Float16* pBu0 = Bu + (size_t)(bn + r0) * RR + gg0 * 8;
  const _Float16* pBu1 = Bu + (size_t)(bn + r1) * RR + gg1 * 8;
  const _Float16* pAw0 = Aw + (size_t)(bm + r0) * DD + gg0 * 8;
  const _Float16* pAw1 = Aw + (size_t)(bm + r1) * DD + gg1 * 8;
  const _Float16* pBw0 = Bw + (size_t)(bn + r0) * DD + gg0 * 8;
  const _Float16* pBw1 = Bw + (size_t)(bn + r1) * DD + gg1 * 8;

  auto stage = [&](int t, int buf) {
    _Float16* la = &As[buf][0][0] + c0 * 512;
    _Float16* lb = &Bs[buf][0][0] + c0 * 512;
    if (t < 6) {
      int k0 = t * BK;
      gload_lds16(pAu0 + k0, la);
      gload_lds16(pAu1 + k0, la + 512);
      gload_lds16(pBu0 + k0, lb);
      gload_lds16(pBu1 + k0, lb + 512);
    } else {
      int k0 = (t - 6) * BK;
      gload_lds16(pAw0 + k0, la);
      gload_lds16(pAw1 + k0, la + 512);
      gload_lds16(pBw0 + k0, lb);
      gload_lds16(pBw1 + k0, lb + 512);
    }
  };

  f32x4 accP[4][4], accS[4][4];
#pragma unroll
  for (int i = 0; i < 4; ++i)
#pragma unroll
    for (int j = 0; j < 4; ++j) {
      accP[i][j] = (f32x4){0.f, 0.f, 0.f, 0.f};
      accS[i][j] = (f32x4){0.f, 0.f, 0.f, 0.f};
    }

  stage(0, 0);
  for (int t = 0; t < 6; ++t) {
    const int cur = t & 1;
    stage(t + 1, cur ^ 1);
    asm volatile("s_waitcnt vmcnt(4)" ::: "memory");
    __builtin_amdgcn_s_barrier();
    asm volatile("" ::: "memory");
    f16x8 Af[4], Bf[4];
#pragma unroll
    for (int i = 0; i < 4; ++i) {
      int ra_ = wm + i * 16 + lm;
      int rb_ = wn + i * 16 + lm;
      Af[i] = *(const f16x8*)&As[cur][ra_][(quad ^ ((ra_ >> 1) & 3)) * 8];
      Bf[i] = *(const f16x8*)&Bs[cur][rb_][(quad ^ ((rb_ >> 1) & 3)) * 8];
    }
#pragma unroll
    for (int i = 0; i < 4; ++i)
#pragma unroll
      for (int j = 0; j < 4; ++j)
        accP[i][j] = __builtin_amdgcn_mfma_f32_16x16x32_f16(Af[i], Bf[j], accP[i][j], 0, 0, 0);
    asm volatile("" ::: "memory");
    __builtin_amdgcn_s_barrier();
  }
  for (int t = 6; t < 30; ++t) {
    const int cur = t & 1;
    if (t < 29) {
      stage(t + 1, cur ^ 1);
      asm volatile("s_waitcnt vmcnt(4)" ::: "memory");
    } else {
      asm volatile("s_waitcnt vmcnt(0)" ::: "memory");
    }
    __builtin_amdgcn_s_barrier();
    asm volatile("" ::: "memory");
    f16x8 Af[4], Bf[4];
#pragma unroll
    for (int i = 0; i < 4; ++i) {
      int ra_ = wm + i * 16 + lm;
      int rb_ = wn + i * 16 + lm;
      Af[i] = *(const f16x8*)&As[cur][ra_][(quad ^ ((ra_ >> 1) & 3)) * 8];
      Bf[i] = *(const f16x8*)&Bs[cur][rb_][(quad ^ ((rb_ >> 1) & 3)) * 8];
    }
#pragma unroll
    for (int i = 0; i < 4; ++i)
#pragma unroll
      for (int j = 0; j < 4; ++j)
        accS[i][j] = __builtin_amdgcn_mfma_f32_16x16x32_f16(Af[i], Bf[j], accS[i][j], 0, 0, 0);
    asm volatile("" ::: "memory");
    __builtin_amdgcn_s_barrier();
  }

  float scale = fminf(expf(p_log_scale[0]), 20.f);
  float qs = L2E / get_eps(p_log_eps);
#pragma unroll
  for (int i = 0; i < 4; ++i)
#pragma unroll
    for (int j = 0; j < 4; ++j) {
      int col = bn + wn + j * 16 + lm;
      if (col >= N) continue;
      float BB = BBv[col];
#pragma unroll
      for (int r = 0; r < 4; ++r) {
        int row = bm + wm + i * 16 + quad * 4 + r;
        float S = accS[i][j][r];
        float mh = fmaxf(AAv[row] + BB - 2.f * (S + accP[i][j][r]), 0.f);
        Sd[(size_t)row * N + col] = fmaf(scale, S, tbias[row]);
        mhq[(size_t)row * VP + col] = (_Float16)(mh * qs);
      }
    }
}

// ---------------------------------------------------------------------------
// P-GEMM + fused epilogue (tight-workspace fallback)
// ---------------------------------------------------------------------------
__global__ __launch_bounds__(256, 2)
void gemm16_p(const _Float16* __restrict__ A, const _Float16* __restrict__ B,
              float* __restrict__ Sd, _Float16* __restrict__ mhq,
              const float* __restrict__ AAv, const float* __restrict__ BBv,
              const float* __restrict__ tbias,
              const float* __restrict__ p_log_scale,
              const float* __restrict__ p_log_eps, int M, int N, int Kd) {
  __shared__ _Float16 As[BM][LDK];
  __shared__ _Float16 Bs[BN][LDK];
  const int tid = threadIdx.x;
  const int bm = blockIdx.y * BM;
  const int bn = blockIdx.x * BN;
  const int srow = tid >> 1;
  const int skb = (tid & 1) << 4;
  const int wave = tid >> 6;
  const int lane = tid & 63;
  const int wm = (wave >> 1) << 6;
  const int wn = (wave & 1) << 6;
  const int lm = lane & 15;
  const int quad = lane >> 4;
  f32x4 acc[4][4];
#pragma unroll
  for (int i = 0; i < 4; ++i)
#pragma unroll
    for (int j = 0; j < 4; ++j) acc[i][j] = (f32x4){0.f, 0.f, 0.f, 0.f};
  const int ra = bm + srow;
  const int rb = bn + srow;
  for (int k0 = 0; k0 < Kd; k0 += BK) {
    f16x8 a0 = (f16x8)(_Float16)0, a1 = a0, b0 = a0, b1 = a0;
    if (ra < M) {
      const f16x8* p = (const f16x8*)(A + (size_t)ra * Kd + k0 + skb);
      a0 = p[0]; a1 = p[1];
    }
    if (rb < N) {
      const f16x8* p = (const f16x8*)(B + (size_t)rb * Kd + k0 + skb);
      b0 = p[0]; b1 = p[1];
    }
    __syncthreads();
    *(f16x8*)&As[srow][skb] = a0; *(f16x8*)&As[srow][skb + 8] = a1;
    *(f16x8*)&Bs[srow][skb] = b0; *(f16x8*)&Bs[srow][skb + 8] = b1;
    __syncthreads();
    f16x8 Af[4], Bf[4];
#pragma unroll
    for (int i = 0; i < 4; ++i) {
      Af[i] = *(const f16x8*)&As[wm + i * 16 + lm][quad * 8];
      Bf[i] = *(const f16x8*)&Bs[wn + i * 16 + lm][quad * 8];
    }
#pragma unroll
    for (int i = 0; i < 4; ++i)
#pragma unroll
      for (int j = 0; j < 4; ++j)
        acc[i][j] = __builtin_amdgcn_mfma_f32_16x16x32_f16(Af[i], Bf[j], acc[i][j], 0, 0, 0);
  }
  float scale = fminf(expf(p_log_scale[0]), 20.f);
  float qs = L2E / get_eps(p_log_eps);
#pragma unroll
  for (int i = 0; i < 4; ++i)
#pragma unroll
    for (int j = 0; j < 4; ++j) {
      int col = bn + wn + j * 16 + lm;
      if (col >= N) continue;
      float BB = BBv[col];
#pragma unroll
      for (int r = 0; r < 4; ++r) {
        int row = bm + wm + i * 16 + quad * 4 + r;
        size_t idx = (size_t)row * N + col;
        float S = Sd[idx];
        float mh = fmaxf(AAv[row] + BB - 2.f * (S + acc[i][j][r]), 0.f);
        Sd[idx] = fmaf(scale, S, tbias[row]);
        mhq[(size_t)row * VP + col] = (_Float16)(mh * qs);
      }
    }
}

// ---------------------------------------------------------------------------
// out[r] = 1 + sum(X16[r,:]^2), cols <= 256
// ---------------------------------------------------------------------------
__global__ __launch_bounds__(256)
void row_sumsq16(const _Float16* __restrict__ X, float* __restrict__ out, int cols) {
  int r = blockIdx.x;
  int t = threadIdx.x;
  float x = (t < cols) ? (float)X[(size_t)r * cols + t] : 0.f;
  __shared__ float red[256];
  red[t] = x * x;
  __syncthreads();
  for (int off = 128; off > 0; off >>= 1) {
    if (t < off) red[t] += red[t + off];
    __syncthreads();
  }
  if (t == 0) out[r] = 1.0f + red[0];
}

// ---------------------------------------------------------------------------
// sink_row0: first Sinkhorn row pass with lv = 0 (matches reference's
// log_v0 = 0). Writes the RAW row sum R0[k] = sum_v 2^(-q[k,v]).
// Max-guards dropped: f32 range analysis shows all terms/sums stay within
// exponent range (q in [0,45], sums <= 5e4*2^0).
// ---------------------------------------------------------------------------
__global__ __launch_bounds__(1024)
void sink_row0(const _Float16* __restrict__ mhq, float* __restrict__ R0) {
  int k = blockIdx.x;
  int t = threadIdx.x;
  const _Float16* row = mhq + (size_t)k * VP;
  float s[8] = {0.f, 0.f, 0.f, 0.f, 0.f, 0.f, 0.f, 0.f};
#pragma unroll
  for (int j = 0; j < 6; ++j) {
    int v = j * 8192 + t * 8;
    f16x8 hv = *(const f16x8*)(row + v);
#pragma unroll
    for (int i = 0; i < 8; ++i) s[i] += fast_exp2(-(float)hv[i]);
  }
  {
    int v = 49152 + t;
    s[0] += fast_exp2(-(float)row[v]);
    v = 50176 + t;
    if (v < VV) s[1] += fast_exp2(-(float)row[v]);
  }
  float sum = ((s[0] + s[1]) + (s[2] + s[3])) + ((s[4] + s[5]) + (s[6] + s[7]));
  __shared__ float red[1024];
  red[t] = sum;
  __syncthreads();
  for (int off = 512; off > 0; off >>= 1) {
    if (t < off) red[t] += red[t + off];
    __syncthreads();
  }
  if (t == 0) R0[k] = red[0];
}

// ---------------------------------------------------------------------------
// sink_step: fused col(i) + row(i+1) pass. One q-read per Sinkhorn iteration
// (vs 2 in the split scheme). Each block owns a 64-col x 512-row panel
// (64 KB), staged to LDS during phase C; phase R re-reads it from LDS.
//   prologue: lu_k = -log2(Rprev[k])          (redundant per block, 2 KB read)
//   phase C:  C_v = sum_k 2^(lu_k - q[k,v]);  lv_v = -log2(C_v)  (in-register)
//   phase R (FINAL=0): partial R'_k = sum_{v in panel} 2^(lv_v - q[k,v])
//             -> one f32 atomicAdd per k per block into Rout (zero-init'd)
//   phase F (FINAL=1): final-logit row sums (old final_sum math) -> Rout =
//             row_s; also writes lv2 (and block 0 writes lu2) for final_write.
// 1024 thr, LDS ~70.4 KB -> 2 blocks/CU = 32 waves/CU. All 16-B loads.
// Lane mapping: c = lane&7 (8-col chunk, fixed per lane), kr = wave*8+lane>>3,
// k = kr + 128*sweep. Edge block (cols >= VV) takes a masked slow path;
// its OOB q reads land in workspace (allocated), contributions zeroed by
// cndmask select (NaN-safe).
// ---------------------------------------------------------------------------
template <int FINAL>
__global__ __launch_bounds__(1024, 2)
void sink_step(const _Float16* __restrict__ mhq, const float* __restrict__ Rprev,
               float* __restrict__ Rout, float* __restrict__ lv2out,
               float* __restrict__ lu2out, const float* __restrict__ direct,
               const float* __restrict__ p_log_eps) {
  __shared__ _Float16 qt[512][64];   // 64 KB
  __shared__ float lu_s[KK];         // 2 KB
  __shared__ float partC[16][64];    // 4 KB
  __shared__ float lv_s[64];
  const int t = threadIdx.x;
  const int wave = t >> 6;
  const int lane = t & 63;
  const int c = lane & 7;                     // col chunk
  const int kr = (wave << 3) + (lane >> 3);   // 0..127
  const int cbase = blockIdx.x * 64;
  if (t < KK) lu_s[t] = -log2f(Rprev[t]);
  __syncthreads();
  // ---- phase C: load panel to LDS + column sums ----
  const _Float16* gsrc = mhq + cbase + c * 8;
  float acc[8] = {0.f, 0.f, 0.f, 0.f, 0.f, 0.f, 0.f, 0.f};
#pragma unroll
  for (int s = 0; s < 4; ++s) {
    int k = kr + s * 128;
    f16x8 hv = *(const f16x8*)(gsrc + (size_t)k * VP);
    *(f16x8*)&qt[k][c * 8] = hv;
    float lu = lu_s[k];
#pragma unroll
    for (int j = 0; j < 8; ++j) acc[j] += fast_exp2(lu - (float)hv[j]);
  }
#pragma unroll
  for (int j = 0; j < 8; ++j) {   // reduce over kr-within-wave (same c)
    acc[j] += __shfl_xor(acc[j], 8);
    acc[j] += __shfl_xor(acc[j], 16);
    acc[j] += __shfl_xor(acc[j], 32);
  }
  if (lane < 8) {
#pragma unroll
    for (int j = 0; j < 8; ++j) partC[wave][lane * 8 + j] = acc[j];
  }
  __syncthreads();
  if (t < 64) {
    float s = 0.f;
#pragma unroll
    for (int w = 0; w < 16; ++w) s += partC[w][t];
    float lv = (cbase + t < VV) ? -log2f(s) : -1e30f;  // mask invalid cols
    lv_s[t] = lv;
    if (FINAL && cbase + t < VV) lv2out[cbase + t] = lv;
  }
  if (FINAL && blockIdx.x == 0 && t < KK) lu2out[t] = lu_s[t];
  __syncthreads();
  float lvr[8];
#pragma unroll
  for (int j = 0; j < 8; ++j) lvr[j] = lv_s[c * 8 + j];
  const bool edge = (cbase + 64 > VV);
  if (!FINAL) {
    // ---- phase R: partial row sums from LDS ----
#pragma unroll
    for (int s = 0; s < 4; ++s) {
      int k = kr + s * 128;
      f16x8 hv = *(const f16x8*)&qt[k][c * 8];
      float sum = 0.f;
      if (!edge) {
#pragma unroll
        for (int j = 0; j < 8; ++j) sum += fast_exp2(lvr[j] - (float)hv[j]);
      } else {
#pragma unroll
        for (int j = 0; j < 8; ++j) {
          float term = fast_exp2(lvr[j] - (float)hv[j]);
          sum += (cbase + c * 8 + j < VV) ? term : 0.f;  // NaN-safe select
        }
      }
      sum += __shfl_xor(sum, 1);
      sum += __shfl_xor(sum, 2);
      sum += __shfl_xor(sum, 4);
      if (c == 0) atomicAdd(&Rout[k], sum);
    }
  } else {
    // ---- phase F: final-logit row sums (== legacy final_sum math) ----
    float eps = get_eps(p_log_eps);
    float c2 = (LAM * eps + GAM) / L2E;
    float c3 = GAM / L2E;
#pragma unroll
    for (int s = 0; s < 4; ++s) {
      int k = kr + s * 128;
      f16x8 hv = *(const f16x8*)&qt[k][c * 8];
      float bl = c3 * lu_s[k];
      const float* dp = direct + (size_t)k * VV + cbase + c * 8;
      float sum = 0.f;
      if (!edge) {
        float d[8];
        *(float4*)&d[0] = *(const float4*)dp;
        *(float4*)&d[4] = *(const float4*)(dp + 4);
#pragma unroll
        for (int j = 0; j < 8; ++j) {
          float x = fmaf(-c2, (float)hv[j], fmaf(c3, lvr[j], d[j] + bl));
          x = fminf(30.f, fmaxf(-30.f, x));
          sum += fast_exp2(fmaf(x, L2E, -30.f * L2E));
        }
      } else {
#pragma unroll
        for (int j = 0; j < 8; ++j) {
          int col = cbase + c * 8 + j;
          bool v = col < VV;
          float d = v ? dp[j] : 0.f;   // guarded load (no OOB)
          float x = fmaf(-c2, (float)hv[j], fmaf(c3, lvr[j], d + bl));
          x = fminf(30.f, fmaxf(-30.f, x));
          float term = fast_exp2(fmaf(x, L2E, -30.f * L2E));
          sum += v ? term : 0.f;
        }
      }
      sum += __shfl_xor(sum, 1);
      sum += __shfl_xor(sum, 2);
      sum += __shfl_xor(sum, 4);
      if (c == 0) atomicAdd(&Rout[k], sum);
    }
  }
}

// ---------------------------------------------------------------------------
// final pass 2: out[k,v] = exp(logit - 30) / row_s[k]
// ---------------------------------------------------------------------------
__global__ __launch_bounds__(256)
void final_write(float* __restrict__ out, const _Float16* __restrict__ mhq,
                 const float* __restrict__ lu2, const float* __restrict__ lv2,
                 const float* __restrict__ row_s, const float* __restrict__ p_log_eps) {
  int v = blockIdx.x * 256 + threadIdx.x;
  int k = blockIdx.y;
  if (v >= VV) return;
  float eps = get_eps(p_log_eps);
  float c2 = (LAM * eps + GAM) / L2E;
  float c3 = GAM / L2E;
  size_t idx = (size_t)k * VV + v;
  float x = fmaf(-c2, (float)mhq[(size_t)k * VP + v],
                 fmaf(c3, lv2[v], out[idx] + c3 * lu2[k]));
  x = fminf(30.f, fmaxf(-30.f, x));
  out[idx] = fast_exp2(fmaf(x, L2E, -30.f * L2E)) / row_s[k];
}

// ---------------------------------------------------------------------------
// launch
// ---------------------------------------------------------------------------
extern "C" void kernel_launch(void* const* d_in, const int* in_sizes, int n_in,
                              void* d_out, int out_size, void* d_ws, size_t ws_size,
                              hipStream_t stream) {
  (void)in_sizes; (void)n_in; (void)out_size;
  const float* WE        = (const float*)d_in[0];
  const float* anchors   = (const float*)d_in[1];
  const float* MU        = (const float*)d_in[2];
  const float* log_eps   = (const float*)d_in[3];
  const float* log_scale = (const float*)d_in[4];
  const float* tbias     = (const float*)d_in[5];
  const float* Wp        = (const float*)d_in[6];
  float* out = (float*)d_out;

  const size_t H_W16 = (size_t)VV * DD;   // 38,597,376 halfs
  const size_t H_MHQ = (size_t)KK * VP;   // 25,739,264 halfs
  const size_t H_WU  = (size_t)VV * RR;
  const size_t H_A16 = (size_t)KK * DD;
  const size_t H_AU  = (size_t)KK * RR;
  const size_t H_UT  = (size_t)RR * DD;
  const size_t FB_FLOATS = 102096 + 11 * KK + 64;  // incl slots + Rbuf
  const size_t need_roomy =
      2 * (H_W16 + H_MHQ + H_WU + H_A16 + H_AU + H_UT) + 4 * FB_FLOATS;
  const bool roomy = ws_size >= need_roomy;

  _Float16* hb = (_Float16*)d_ws;
  _Float16* w16 = hb;
  size_t ho = H_W16;
  _Float16* mhq;
  if (roomy) { mhq = hb + ho; ho += H_MHQ; }
  else       { mhq = hb; }                 // alias w16 (dead after S GEMM)
  _Float16* wU16 = hb + ho; ho += H_WU;
  _Float16* a16  = hb + ho; ho += H_A16;
  _Float16* aU16 = hb + ho; ho += H_AU;
  _Float16* Ut16 = hb + ho; ho += H_UT;
  float* fb = (float*)(hb + ho);
  float* BBv   = fb;           // 50264
  float* AAv   = fb + 50264;   // 512
  float* lu2   = fb + 50776;   // 512
  float* lv2   = fb + 51288;   // 50264
  unsigned* slots = (unsigned*)(fb + 102064);  // 32
  float* Rbuf  = fb + 102096;  // [11][512]
  unsigned* eye_flag = slots + 24;

  const int VB = (VV + 255) / 256;      // 197
  const int MB_V = (VV + BM - 1) / BM;  // 393
  const int NSB = (VV + 63) / 64;       // 786 sink_step panels

  prep<<<1111, 256, 0, stream>>>(MU, slots, anchors, Ut16, a16, Rbuf);
  check_eye<<<(DD * DD + 255) / 256, 256, 0, stream>>>(Wp, eye_flag);
  gemm_we_fallback<<<dim3(DD / BN, MB_V), 256, 0, stream>>>(WE, Wp, w16, VV, DD, DD, eye_flag);
  norm_w<<<VV, 256, 0, stream>>>(WE, w16, eye_flag);
  gemm16<1><<<dim3(2, MB_V), 256, 0, stream>>>(w16, Ut16, wU16, VV, RR, DD);
  gemm16<1><<<dim3(2, 4), 256, 0, stream>>>(a16, Ut16, aU16, KK, RR, DD);
  row_sumsq16<<<VV, 256, 0, stream>>>(wU16, BBv, RR);
  row_sumsq16<<<KK, 256, 0, stream>>>(aU16, AAv, RR);
  if (roomy) {
    gemm_sp<<<dim3(4, MB_V), 256, 0, stream>>>(a16, w16, aU16, wU16, out, mhq,
                                               AAv, BBv, tbias, log_scale,
                                               log_eps, KK, VV);
  } else {
    gemm16<0><<<dim3(MB_V, 4), 256, 0, stream>>>(a16, w16, out, KK, VV, DD);
    gemm16_p<<<dim3(MB_V, 4), 256, 0, stream>>>(aU16, wU16, out, mhq, AAv, BBv,
                                                tbias, log_scale, log_eps, KK, VV, RR);
  }
  // Sinkhorn: row_1 standalone, then 10 fused col+row steps (last = final)
  sink_row0<<<KK, 1024, 0, stream>>>(mhq, Rbuf);
  for (int it = 1; it <= 9; ++it)
    sink_step<0><<<NSB, 1024, 0, stream>>>(mhq, Rbuf + (it - 1) * KK,
                                           Rbuf + it * KK, lv2, lu2, out, log_eps);
  sink_step<1><<<NSB, 1024, 0, stream>>>(mhq, Rbuf + 9 * KK, Rbuf + 10 * KK,
                                         lv2, lu2, out, log_eps);
  final_write<<<dim3(VB, KK), 256, 0, stream>>>(out, mhq, lu2, lv2,
                                                Rbuf + 10 * KK, log_eps);
}